// Round 1
// baseline (1093.250 us; speedup 1.0000x reference)
//
#include <hip/hip_runtime.h>
#include <stdint.h>
#include <stddef.h>

#define Bsz   2
#define Ssz   2048
#define HIDsz 4096
#define Hsz   32
#define KVsz  8
#define Dsz   128
#define NQKV  6144                     // (H+2KV)*D
#define RSCALE 0.08838834764831845f    // 1/sqrt(128)

typedef __bf16 bf16x8 __attribute__((ext_vector_type(8)));
typedef float  f32x4  __attribute__((ext_vector_type(4)));
typedef unsigned short u16;
typedef u16 u16x4 __attribute__((ext_vector_type(4)));
typedef u16 u16x8 __attribute__((ext_vector_type(8)));

__device__ __forceinline__ u16 f2bf(float f) {
  uint32_t u = __builtin_bit_cast(uint32_t, f);
  u = (u + 0x7FFFu + ((u >> 16) & 1u)) >> 16;   // RNE
  return (u16)u;
}
__device__ __forceinline__ float bf2f(u16 h) {
  return __builtin_bit_cast(float, (uint32_t)h << 16);
}

// global -> LDS async copy, 16B per lane; LDS dest = wave-uniform base + lane*16
#define GLDS(gp, lp) __builtin_amdgcn_global_load_lds( \
    (__attribute__((address_space(1))) void*)(void*)(gp), \
    (__attribute__((address_space(3))) void*)(lp), 16, 0, 0)

// ---------------- elementwise conversions ----------------
__global__ __launch_bounds__(256) void k_cvt_bf16(const float* __restrict__ in,
                                                  u16* __restrict__ out, int n4) {
  int i = blockIdx.x * 256 + threadIdx.x;
  if (i >= n4) return;
  float4 v = ((const float4*)in)[i];
  u16x4 o;
  o.x = f2bf(v.x); o.y = f2bf(v.y); o.z = f2bf(v.z); o.w = f2bf(v.w);
  ((u16x4*)out)[i] = o;
}

// cos/sin table [B*S][64]
__global__ __launch_bounds__(256) void k_cs(const int* __restrict__ pos,
                                            float* __restrict__ cosT,
                                            float* __restrict__ sinT) {
  int idx = blockIdx.x * 256 + threadIdx.x;       // B*S*64
  if (idx >= Bsz * Ssz * 64) return;
  int j = idx & 63;
  int bs = idx >> 6;
  float p = (float)pos[bs];
  // inv_freq = 10000^(-j/64) = exp(-j * ln(10000)/64)
  float inv = __expf(-(float)j * (9.210340371976184f / 64.0f));
  float ang = p * inv;
  cosT[idx] = __cosf(ang);
  sinT[idx] = __sinf(ang);
}

// RoPE on q,k; q scaled by 1/sqrt(D); writes Qr[b][h][s][d], Kr[b][kvh][s][d]
__global__ __launch_bounds__(256) void k_rope(const u16* __restrict__ qkv,
                                              const float* __restrict__ cosT,
                                              const float* __restrict__ sinT,
                                              u16* __restrict__ Qr, u16* __restrict__ Kr) {
  int idx = blockIdx.x * 256 + threadIdx.x;       // B*S*(H+KV)*64
  if (idx >= Bsz * Ssz * (Hsz + KVsz) * 64) return;
  int j = idx & 63;
  int head = (idx >> 6) % (Hsz + KVsz);
  int bs = idx / (64 * (Hsz + KVsz));
  const u16* row = qkv + (size_t)bs * NQKV + head * Dsz;
  float x1 = bf2f(row[j]), x2 = bf2f(row[j + 64]);
  float c = cosT[bs * 64 + j], s = sinT[bs * 64 + j];
  float o1 = x1 * c - x2 * s;
  float o2 = x2 * c + x1 * s;
  int b = bs / Ssz, sidx = bs % Ssz;
  if (head < Hsz) {
    u16* o = Qr + ((size_t)(b * Hsz + head) * Ssz + sidx) * Dsz;
    o[j] = f2bf(o1 * RSCALE); o[j + 64] = f2bf(o2 * RSCALE);
  } else {
    int kvh = head - Hsz;
    u16* o = Kr + ((size_t)(b * KVsz + kvh) * Ssz + sidx) * Dsz;
    o[j] = f2bf(o1); o[j + 64] = f2bf(o2);
  }
}

// V transpose: Vt[b][kvh][d][s] = qkv[b,s, (H+KV)*D + kvh*D + d]
__global__ __launch_bounds__(256) void k_vtrans(const u16* __restrict__ qkv,
                                                u16* __restrict__ Vt) {
  int idx = blockIdx.x * 256 + threadIdx.x;       // B*KV*D*S
  if (idx >= Bsz * KVsz * Dsz * Ssz) return;
  int s = idx % Ssz;
  int rest = idx / Ssz;
  int d = rest % Dsz;
  int bk = rest / Dsz;
  int b = bk / KVsz, kvh = bk % KVsz;
  Vt[idx] = qkv[(size_t)(b * Ssz + s) * NQKV + (Hsz + KVsz) * Dsz + kvh * Dsz + d];
}

// ---------------- GEMM: C[M][N] = A[M][K] * B[N][K]^T (bf16 in, f32 acc) ----------------
template <bool BF16OUT>
__global__ __launch_bounds__(256) void k_gemm(const u16* __restrict__ A,
                                              const u16* __restrict__ Bm,
                                              void* __restrict__ Cv,
                                              int M, int N, int K) {
  __shared__ __align__(16) u16 As[128 * 64];
  __shared__ __align__(16) u16 Bs[128 * 64];
  const int tid = threadIdx.x;
  const int w = tid >> 6, lane = tid & 63;
  const int g = lane >> 4, t = lane & 15;
  const int wm = w >> 1, wn = w & 1;
  const int m0 = blockIdx.y * 128, n0 = blockIdx.x * 128;
  const int rsub = lane >> 3, csub = (lane & 7) * 8;

  f32x4 acc[4][4];
#pragma unroll
  for (int i = 0; i < 4; ++i)
#pragma unroll
    for (int j = 0; j < 4; ++j) acc[i][j] = (f32x4){0.f, 0.f, 0.f, 0.f};

  for (int k0 = 0; k0 < K; k0 += 64) {
#pragma unroll
    for (int i = 0; i < 4; ++i) {
      int rb = (w * 4 + i) * 8;                  // 8 rows per wave-inst
      GLDS(A  + (size_t)(m0 + rb + rsub) * K + k0 + csub, &As[rb * 64]);
      GLDS(Bm + (size_t)(n0 + rb + rsub) * K + k0 + csub, &Bs[rb * 64]);
    }
    __syncthreads();
#pragma unroll
    for (int ks = 0; ks < 64; ks += 32) {
      bf16x8 af[4], bfr[4];
#pragma unroll
      for (int i = 0; i < 4; ++i)
        af[i] = __builtin_bit_cast(bf16x8, *(const u16x8*)&As[(wm * 64 + i * 16 + t) * 64 + ks + 8 * g]);
#pragma unroll
      for (int j = 0; j < 4; ++j)
        bfr[j] = __builtin_bit_cast(bf16x8, *(const u16x8*)&Bs[(wn * 64 + j * 16 + t) * 64 + ks + 8 * g]);
#pragma unroll
      for (int i = 0; i < 4; ++i)
#pragma unroll
        for (int j = 0; j < 4; ++j)
          acc[i][j] = __builtin_amdgcn_mfma_f32_16x16x32_bf16(af[i], bfr[j], acc[i][j], 0, 0, 0);
    }
    __syncthreads();
  }
#pragma unroll
  for (int i = 0; i < 4; ++i)
#pragma unroll
    for (int j = 0; j < 4; ++j)
#pragma unroll
      for (int r = 0; r < 4; ++r) {
        int row = m0 + wm * 64 + i * 16 + 4 * g + r;
        int col = n0 + wn * 64 + j * 16 + t;
        float v = acc[i][j][r];
        if constexpr (BF16OUT) ((u16*)Cv)[(size_t)row * N + col] = f2bf(v);
        else                   ((float*)Cv)[(size_t)row * N + col] = v;
      }
}

// ---------------- flash attention (causal, GQA) ----------------
// grid (S/64, B*H); 4 waves, each wave owns 16 q-rows; KV tiles of 64.
__global__ __launch_bounds__(256) void k_attn(const u16* __restrict__ Qr,
                                              const u16* __restrict__ Kr,
                                              const u16* __restrict__ Vt,
                                              u16* __restrict__ AO) {
  __shared__ __align__(16) u16 Kl[64 * 128];     // [k][d]
  __shared__ __align__(16) u16 Vl[128 * 64];     // [d][k]
  __shared__ __align__(16) u16 Pl[4][16 * 72];   // per-wave P, padded stride 72
  const int tid = threadIdx.x;
  const int w = tid >> 6, lane = tid & 63;
  const int g = lane >> 4, t = lane & 15;
  const int bh = blockIdx.y;
  const int b = bh >> 5, h = bh & 31;
  const int kvh = h >> 2;                        // GQA: H/KV = 4
  const int q0 = blockIdx.x * 64;
  const int qw = q0 + w * 16;

  const u16* Qb = Qr + ((size_t)bh * Ssz + qw + t) * Dsz;
  bf16x8 qf[4];
#pragma unroll
  for (int ks = 0; ks < 4; ++ks)
    qf[ks] = __builtin_bit_cast(bf16x8, *(const u16x8*)(Qb + ks * 32 + 8 * g));

  f32x4 oacc[8];
#pragma unroll
  for (int db = 0; db < 8; ++db) oacc[db] = (f32x4){0.f, 0.f, 0.f, 0.f};
  float mrow[4] = {-1e30f, -1e30f, -1e30f, -1e30f};
  float lrow[4] = {0.f, 0.f, 0.f, 0.f};

  const u16* Kbase = Kr + (size_t)(b * KVsz + kvh) * Ssz * Dsz;
  const u16* Vbase = Vt + (size_t)(b * KVsz + kvh) * Dsz * Ssz;

  const int ntiles = blockIdx.x + 1;
  for (int kt = 0; kt < ntiles; ++kt) {
    const int k0 = kt * 64;
    {
      int rs = lane >> 4, cs = (lane & 15) * 8;  // K tile: 4 rows / wave-inst
#pragma unroll
      for (int i = 0; i < 4; ++i) {
        int rb = (w * 4 + i) * 4;
        GLDS(Kbase + (size_t)(k0 + rb + rs) * 128 + cs, &Kl[rb * 128]);
      }
      int rs2 = lane >> 3, cs2 = (lane & 7) * 8; // Vt tile: 8 rows / wave-inst
#pragma unroll
      for (int i = 0; i < 4; ++i) {
        int rb = (w * 4 + i) * 8;
        GLDS(Vbase + (size_t)(rb + rs2) * Ssz + k0 + cs2, &Vl[rb * 64]);
      }
    }
    __syncthreads();

    // QK^T : 16 q-rows x 64 k-cols
    f32x4 sc[4];
#pragma unroll
    for (int cb = 0; cb < 4; ++cb) {
      f32x4 a = (f32x4){0.f, 0.f, 0.f, 0.f};
#pragma unroll
      for (int ks = 0; ks < 4; ++ks) {
        bf16x8 kf = __builtin_bit_cast(bf16x8, *(const u16x8*)&Kl[(cb * 16 + t) * 128 + ks * 32 + 8 * g]);
        a = __builtin_amdgcn_mfma_f32_16x16x32_bf16(qf[ks], kf, a, 0, 0, 0);
      }
      sc[cb] = a;
    }

    const bool diag = (kt == ntiles - 1);
    float corr[4];
#pragma unroll
    for (int r = 0; r < 4; ++r) {
      int qg = qw + 4 * g + r;
      if (diag) {
#pragma unroll
        for (int cb = 0; cb < 4; ++cb) {
          int kg = k0 + cb * 16 + t;
          if (kg > qg) sc[cb][r] = -1e30f;
        }
      }
      float tm = fmaxf(fmaxf(sc[0][r], sc[1][r]), fmaxf(sc[2][r], sc[3][r]));
#pragma unroll
      for (int m = 1; m < 16; m <<= 1) tm = fmaxf(tm, __shfl_xor(tm, m, 64));
      float mnew = fmaxf(mrow[r], tm);
      corr[r] = __expf(mrow[r] - mnew);
      float ps = 0.f;
#pragma unroll
      for (int cb = 0; cb < 4; ++cb) {
        float p = __expf(sc[cb][r] - mnew);
        sc[cb][r] = p; ps += p;
      }
#pragma unroll
      for (int m = 1; m < 16; m <<= 1) ps += __shfl_xor(ps, m, 64);
      lrow[r] = lrow[r] * corr[r] + ps;
      mrow[r] = mnew;
    }
#pragma unroll
    for (int db = 0; db < 8; ++db) {
      f32x4 o = oacc[db];
      o[0] *= corr[0]; o[1] *= corr[1]; o[2] *= corr[2]; o[3] *= corr[3];
      oacc[db] = o;
    }
    // P -> LDS (bf16), then consume as MFMA A-operand
#pragma unroll
    for (int r = 0; r < 4; ++r)
#pragma unroll
      for (int cb = 0; cb < 4; ++cb)
        Pl[w][(4 * g + r) * 72 + cb * 16 + t] = f2bf(sc[cb][r]);
    asm volatile("s_waitcnt lgkmcnt(0)" ::: "memory");   // cross-lane RAW within wave
#pragma unroll
    for (int ks2 = 0; ks2 < 2; ++ks2) {
      bf16x8 pf = __builtin_bit_cast(bf16x8, *(const u16x8*)&Pl[w][t * 72 + ks2 * 32 + 8 * g]);
#pragma unroll
      for (int db = 0; db < 8; ++db) {
        bf16x8 vf = __builtin_bit_cast(bf16x8, *(const u16x8*)&Vl[(db * 16 + t) * 64 + ks2 * 32 + 8 * g]);
        oacc[db] = __builtin_amdgcn_mfma_f32_16x16x32_bf16(pf, vf, oacc[db], 0, 0, 0);
      }
    }
    __syncthreads();
  }
#pragma unroll
  for (int r = 0; r < 4; ++r) {
    float inv = 1.f / lrow[r];
    size_t orow = ((size_t)b * Ssz + qw + 4 * g + r) * (size_t)HIDsz + h * Dsz;
#pragma unroll
    for (int db = 0; db < 8; ++db)
      AO[orow + db * 16 + t] = f2bf(oacc[db][r] * inv);
  }
}

// ---------------- host ----------------
extern "C" void kernel_launch(void* const* d_in, const int* in_sizes, int n_in,
                              void* d_out, int out_size, void* d_ws, size_t ws_size,
                              hipStream_t stream) {
  (void)in_sizes; (void)n_in; (void)out_size;
  const float* hs   = (const float*)d_in[0];
  const int*   pos  = (const int*)d_in[1];
  const float* Wqkv = (const float*)d_in[2];
  const float* Wo   = (const float*)d_in[3];

  char* ws = (char*)d_ws;
  const size_t SZ_XBF = (size_t)4096 * 4096 * 2;   // also reused for AO
  const size_t SZ_WQ  = (size_t)6144 * 4096 * 2;
  const size_t SZ_WO  = (size_t)4096 * 4096 * 2;
  const size_t SZ_QKV = (size_t)4096 * 6144 * 2;
  const size_t SZ_QR  = (size_t)Bsz * Hsz * Ssz * Dsz * 2;
  const size_t SZ_KR  = (size_t)Bsz * KVsz * Ssz * Dsz * 2;
  const size_t SZ_VT  = SZ_KR;
  const size_t SZ_CS  = (size_t)Bsz * Ssz * 64 * 4;

  size_t off = 0;
  u16*   Xbf   = (u16*)(ws + off);  off += SZ_XBF;
  u16*   Wq_bf = (u16*)(ws + off);  off += SZ_WQ;
  u16*   Wo_bf = (u16*)(ws + off);  off += SZ_WO;
  u16*   qkv   = (u16*)(ws + off);  off += SZ_QKV;
  u16*   Qr    = (u16*)(ws + off);  off += SZ_QR;
  u16*   Kr    = (u16*)(ws + off);  off += SZ_KR;
  u16*   Vt    = (u16*)(ws + off);  off += SZ_VT;
  float* cosT  = (float*)(ws + off); off += SZ_CS;
  float* sinT  = (float*)(ws + off); off += SZ_CS;
  u16*   AO    = Xbf;                               // alias (Xbf dead after gemm1)
  if (ws_size < off) return;                        // fail loudly

  // 1. fp32 -> bf16 conversions
  k_cvt_bf16<<<(Bsz * Ssz * HIDsz) / 1024, 256, 0, stream>>>(hs, Xbf, (Bsz * Ssz * HIDsz) / 4);
  k_cvt_bf16<<<(NQKV * HIDsz) / 1024, 256, 0, stream>>>(Wqkv, Wq_bf, (NQKV * HIDsz) / 4);
  k_cvt_bf16<<<(HIDsz * HIDsz) / 1024, 256, 0, stream>>>(Wo, Wo_bf, (HIDsz * HIDsz) / 4);

  // 2. QKV projection: [4096,4096] x [6144,4096]^T -> [4096,6144]
  k_gemm<true><<<dim3(NQKV / 128, (Bsz * Ssz) / 128), 256, 0, stream>>>(Xbf, Wq_bf, qkv, Bsz * Ssz, NQKV, HIDsz);

  // 3. RoPE tables + apply + V transpose
  k_cs<<<(Bsz * Ssz * 64) / 256, 256, 0, stream>>>(pos, cosT, sinT);
  k_rope<<<(Bsz * Ssz * (Hsz + KVsz) * 64) / 256, 256, 0, stream>>>(qkv, cosT, sinT, Qr, Kr);
  k_vtrans<<<(Bsz * KVsz * Dsz * Ssz) / 256, 256, 0, stream>>>(qkv, Vt);

  // 4. causal GQA attention -> AO [B,S,H*D] bf16
  k_attn<<<dim3(Ssz / 64, Bsz * Hsz), 256, 0, stream>>>(Qr, Kr, Vt, AO);

  // 5. o_proj: [4096,4096] x [4096,4096]^T -> d_out fp32
  k_gemm<false><<<dim3(HIDsz / 128, (Bsz * Ssz) / 128), 256, 0, stream>>>(AO, Wo_bf, (float*)d_out, Bsz * Ssz, HIDsz, HIDsz);
}

// Round 2
// 896.093 us; speedup vs baseline: 1.2200x; 1.2200x over previous
//
#include <hip/hip_runtime.h>
#include <stdint.h>
#include <stddef.h>

#define Bsz   2
#define Ssz   2048
#define HIDsz 4096
#define Hsz   32
#define KVsz  8
#define Dsz   128
#define NQKV  6144                     // (H+2KV)*D
#define RSCALE 0.08838834764831845f    // 1/sqrt(128)

typedef __bf16 bf16x8 __attribute__((ext_vector_type(8)));
typedef float  f32x4  __attribute__((ext_vector_type(4)));
typedef unsigned short u16;
typedef u16 u16x4 __attribute__((ext_vector_type(4)));
typedef u16 u16x8 __attribute__((ext_vector_type(8)));

__device__ __forceinline__ u16 f2bf(float f) {
  uint32_t u = __builtin_bit_cast(uint32_t, f);
  u = (u + 0x7FFFu + ((u >> 16) & 1u)) >> 16;   // RNE
  return (u16)u;
}
__device__ __forceinline__ u16 f2bf_fast(float f) {  // round-half-up, 2 VALU
  uint32_t u = __builtin_bit_cast(uint32_t, f);
  return (u16)((u + 0x8000u) >> 16);
}
__device__ __forceinline__ float bf2f(u16 h) {
  return __builtin_bit_cast(float, (uint32_t)h << 16);
}

// global -> LDS async copy, 16B per lane; LDS dest = wave-uniform base + lane*16
#define GLDS(gp, lp) __builtin_amdgcn_global_load_lds( \
    (__attribute__((address_space(1))) void*)(void*)(gp), \
    (__attribute__((address_space(3))) void*)(lp), 16, 0, 0)

// ---------------- elementwise conversions ----------------
__global__ __launch_bounds__(256) void k_cvt_bf16(const float* __restrict__ in,
                                                  u16* __restrict__ out, int n4) {
  int i = blockIdx.x * 256 + threadIdx.x;
  if (i >= n4) return;
  float4 v = ((const float4*)in)[i];
  u16x4 o;
  o.x = f2bf(v.x); o.y = f2bf(v.y); o.z = f2bf(v.z); o.w = f2bf(v.w);
  ((u16x4*)out)[i] = o;
}

// cos/sin table [B*S][64]
__global__ __launch_bounds__(256) void k_cs(const int* __restrict__ pos,
                                            float* __restrict__ cosT,
                                            float* __restrict__ sinT) {
  int idx = blockIdx.x * 256 + threadIdx.x;       // B*S*64
  if (idx >= Bsz * Ssz * 64) return;
  int j = idx & 63;
  int bs = idx >> 6;
  float p = (float)pos[bs];
  float inv = __expf(-(float)j * (9.210340371976184f / 64.0f));
  float ang = p * inv;
  cosT[idx] = __cosf(ang);
  sinT[idx] = __sinf(ang);
}

// RoPE on q,k; q scaled by 1/sqrt(D); writes Qr[b][h][s][d], Kr[b][kvh][s][d]
__global__ __launch_bounds__(256) void k_rope(const u16* __restrict__ qkv,
                                              const float* __restrict__ cosT,
                                              const float* __restrict__ sinT,
                                              u16* __restrict__ Qr, u16* __restrict__ Kr) {
  int idx = blockIdx.x * 256 + threadIdx.x;       // B*S*(H+KV)*64
  if (idx >= Bsz * Ssz * (Hsz + KVsz) * 64) return;
  int j = idx & 63;
  int head = (idx >> 6) % (Hsz + KVsz);
  int bs = idx / (64 * (Hsz + KVsz));
  const u16* row = qkv + (size_t)bs * NQKV + head * Dsz;
  float x1 = bf2f(row[j]), x2 = bf2f(row[j + 64]);
  float c = cosT[bs * 64 + j], s = sinT[bs * 64 + j];
  float o1 = x1 * c - x2 * s;
  float o2 = x2 * c + x1 * s;
  int b = bs / Ssz, sidx = bs % Ssz;
  if (head < Hsz) {
    u16* o = Qr + ((size_t)(b * Hsz + head) * Ssz + sidx) * Dsz;
    o[j] = f2bf(o1 * RSCALE); o[j + 64] = f2bf(o2 * RSCALE);
  } else {
    int kvh = head - Hsz;
    u16* o = Kr + ((size_t)(b * KVsz + kvh) * Ssz + sidx) * Dsz;
    o[j] = f2bf(o1); o[j + 64] = f2bf(o2);
  }
}

// V transpose: Vt[b][kvh][d][s] = qkv[b,s, (H+KV)*D + kvh*D + d]
__global__ __launch_bounds__(256) void k_vtrans(const u16* __restrict__ qkv,
                                                u16* __restrict__ Vt) {
  int idx = blockIdx.x * 256 + threadIdx.x;       // B*KV*D*S
  if (idx >= Bsz * KVsz * Dsz * Ssz) return;
  int s = idx % Ssz;
  int rest = idx / Ssz;
  int d = rest % Dsz;
  int bk = rest / Dsz;
  int b = bk / KVsz, kvh = bk % KVsz;
  Vt[idx] = qkv[(size_t)(b * Ssz + s) * NQKV + (Hsz + KVsz) * Dsz + kvh * Dsz + d];
}

// ---------------- GEMM: C[M][N] = A[M][K] * B[N][K]^T (bf16 in, f32 acc) ----------------
template <bool BF16OUT>
__global__ __launch_bounds__(256) void k_gemm(const u16* __restrict__ A,
                                              const u16* __restrict__ Bm,
                                              void* __restrict__ Cv,
                                              int M, int N, int K) {
  __shared__ __align__(16) u16 As[128 * 64];
  __shared__ __align__(16) u16 Bs[128 * 64];
  const int tid = threadIdx.x;
  const int w = tid >> 6, lane = tid & 63;
  const int g = lane >> 4, t = lane & 15;
  const int wm = w >> 1, wn = w & 1;
  const int m0 = blockIdx.y * 128, n0 = blockIdx.x * 128;
  const int rsub = lane >> 3, csub = (lane & 7) * 8;

  f32x4 acc[4][4];
#pragma unroll
  for (int i = 0; i < 4; ++i)
#pragma unroll
    for (int j = 0; j < 4; ++j) acc[i][j] = (f32x4){0.f, 0.f, 0.f, 0.f};

  for (int k0 = 0; k0 < K; k0 += 64) {
#pragma unroll
    for (int i = 0; i < 4; ++i) {
      int rb = (w * 4 + i) * 8;                  // 8 rows per wave-inst
      GLDS(A  + (size_t)(m0 + rb + rsub) * K + k0 + csub, &As[rb * 64]);
      GLDS(Bm + (size_t)(n0 + rb + rsub) * K + k0 + csub, &Bs[rb * 64]);
    }
    __syncthreads();
#pragma unroll
    for (int ks = 0; ks < 64; ks += 32) {
      bf16x8 af[4], bfr[4];
#pragma unroll
      for (int i = 0; i < 4; ++i)
        af[i] = __builtin_bit_cast(bf16x8, *(const u16x8*)&As[(wm * 64 + i * 16 + t) * 64 + ks + 8 * g]);
#pragma unroll
      for (int j = 0; j < 4; ++j)
        bfr[j] = __builtin_bit_cast(bf16x8, *(const u16x8*)&Bs[(wn * 64 + j * 16 + t) * 64 + ks + 8 * g]);
#pragma unroll
      for (int i = 0; i < 4; ++i)
#pragma unroll
        for (int j = 0; j < 4; ++j)
          acc[i][j] = __builtin_amdgcn_mfma_f32_16x16x32_bf16(af[i], bfr[j], acc[i][j], 0, 0, 0);
    }
    __syncthreads();
  }
#pragma unroll
  for (int i = 0; i < 4; ++i)
#pragma unroll
    for (int j = 0; j < 4; ++j)
#pragma unroll
      for (int r = 0; r < 4; ++r) {
        int row = m0 + wm * 64 + i * 16 + 4 * g + r;
        int col = n0 + wn * 64 + j * 16 + t;
        float v = acc[i][j][r];
        if constexpr (BF16OUT) ((u16*)Cv)[(size_t)row * N + col] = f2bf(v);
        else                   ((float*)Cv)[(size_t)row * N + col] = v;
      }
}

// ---------------- flash attention (causal, GQA) ----------------
// grid (S/64, B*H); 4 waves, each wave owns 16 q-rows; KV tiles of 64.
// T2 both-sides XOR swizzle on K and V tiles; T3 2-phase double-buffered
// prefetch; T5 setprio around MFMA; longest-blocks-first grid order.
__global__ __launch_bounds__(256) void k_attn(const u16* __restrict__ Qr,
                                              const u16* __restrict__ Kr,
                                              const u16* __restrict__ Vt,
                                              u16* __restrict__ AO) {
  __shared__ __align__(16) u16 Kl[2][64 * 128];  // [k][d], 256B rows, swizzled
  __shared__ __align__(16) u16 Vl[2][128 * 64];  // [d][k], 128B rows, swizzled
  __shared__ __align__(16) u16 Pl[4][16 * 72];   // per-wave P, padded stride 72
  const int tid = threadIdx.x;
  const int w = tid >> 6, lane = tid & 63;
  const int g = lane >> 4, t = lane & 15;
  const int bh = blockIdx.y;
  const int b = bh >> 5, h = bh & 31;
  const int kvh = h >> 2;                        // GQA: H/KV = 4
  const int bxr = gridDim.x - 1 - blockIdx.x;    // longest blocks dispatch first
  const int q0 = bxr * 64;
  const int qw = q0 + w * 16;
  const int ntiles = bxr + 1;
  const int lx = (t & 7) << 4;                   // read-side XOR (bytes)

  const u16* Qb = Qr + ((size_t)bh * Ssz + qw + t) * Dsz;
  bf16x8 qf[4];
#pragma unroll
  for (int ks = 0; ks < 4; ++ks)
    qf[ks] = __builtin_bit_cast(bf16x8, *(const u16x8*)(Qb + ks * 32 + 8 * g));

  f32x4 oacc[8];
#pragma unroll
  for (int db = 0; db < 8; ++db) oacc[db] = (f32x4){0.f, 0.f, 0.f, 0.f};
  float mrow[4] = {-1e30f, -1e30f, -1e30f, -1e30f};
  float lrow[4] = {0.f, 0.f, 0.f, 0.f};

  const char* Kbase = (const char*)(Kr + (size_t)(b * KVsz + kvh) * Ssz * Dsz);
  const char* Vbase = (const char*)(Vt + (size_t)(b * KVsz + kvh) * Dsz * Ssz);

  // stage tile kt2 into buffer bu: LDS dest linear, global source inverse-swizzled
  auto STAGE = [&](int bu, int kt2) {
    const int k0s = kt2 * 64;
#pragma unroll
    for (int i = 0; i < 4; ++i) {                // K: 4 rows (256B) per inst
      int rb = (w * 4 + i) * 4;
      int row = rb + (lane >> 4);
      int colb = ((lane & 15) * 16) ^ ((row & 7) << 4);
      GLDS(Kbase + ((size_t)(k0s + row) * 256 + colb), &Kl[bu][rb * 128]);
    }
#pragma unroll
    for (int i = 0; i < 4; ++i) {                // V: 8 rows (128B) per inst
      int rb = (w * 4 + i) * 8;
      int row = rb + (lane >> 3);
      int colb = ((lane & 7) * 16) ^ ((row & 7) << 4);
      GLDS(Vbase + ((size_t)row * (Ssz * 2) + (size_t)k0s * 2 + colb), &Vl[bu][rb * 64]);
    }
  };

  int buf = 0;
  STAGE(0, 0);
  __syncthreads();

  for (int kt = 0; kt < ntiles; ++kt) {
    const int k0 = kt * 64;
    if (kt + 1 < ntiles) STAGE(buf ^ 1, kt + 1);   // prefetch overlaps compute

    // QK^T : 16 q-rows x 64 k-cols
    f32x4 sc[4];
    __builtin_amdgcn_s_setprio(1);
#pragma unroll
    for (int cb = 0; cb < 4; ++cb) {
      f32x4 a = (f32x4){0.f, 0.f, 0.f, 0.f};
#pragma unroll
      for (int ks = 0; ks < 4; ++ks) {
        int coff = ((ks * 64 + 16 * g) ^ lx) >> 1;   // swizzled elem offset
        bf16x8 kf = __builtin_bit_cast(bf16x8, *(const u16x8*)&Kl[buf][(cb * 16 + t) * 128 + coff]);
        a = __builtin_amdgcn_mfma_f32_16x16x32_bf16(qf[ks], kf, a, 0, 0, 0);
      }
      sc[cb] = a;
    }
    __builtin_amdgcn_s_setprio(0);

    const bool diag = (kt == ntiles - 1);
    float corr[4];
#pragma unroll
    for (int r = 0; r < 4; ++r) {
      int qg = qw + 4 * g + r;
      if (diag) {
#pragma unroll
        for (int cb = 0; cb < 4; ++cb) {
          int kg = k0 + cb * 16 + t;
          if (kg > qg) sc[cb][r] = -1e30f;
        }
      }
      float tm = fmaxf(fmaxf(sc[0][r], sc[1][r]), fmaxf(sc[2][r], sc[3][r]));
#pragma unroll
      for (int m = 1; m < 16; m <<= 1) tm = fmaxf(tm, __shfl_xor(tm, m, 64));
      float mnew = fmaxf(mrow[r], tm);
      corr[r] = __expf(mrow[r] - mnew);
      float ps = 0.f;
#pragma unroll
      for (int cb = 0; cb < 4; ++cb) {
        float p = __expf(sc[cb][r] - mnew);
        sc[cb][r] = p; ps += p;
      }
#pragma unroll
      for (int m = 1; m < 16; m <<= 1) ps += __shfl_xor(ps, m, 64);
      lrow[r] = lrow[r] * corr[r] + ps;
      mrow[r] = mnew;
    }
#pragma unroll
    for (int db = 0; db < 8; ++db) {
      f32x4 o = oacc[db];
      o[0] *= corr[0]; o[1] *= corr[1]; o[2] *= corr[2]; o[3] *= corr[3];
      oacc[db] = o;
    }
    // P -> LDS (bf16), then consume as MFMA A-operand
#pragma unroll
    for (int r = 0; r < 4; ++r)
#pragma unroll
      for (int cb = 0; cb < 4; ++cb)
        Pl[w][(4 * g + r) * 72 + cb * 16 + t] = f2bf_fast(sc[cb][r]);
    asm volatile("s_waitcnt lgkmcnt(0)" ::: "memory");   // DS in-order: writes done
    __builtin_amdgcn_s_setprio(1);
#pragma unroll
    for (int ks2 = 0; ks2 < 2; ++ks2) {
      bf16x8 pf = __builtin_bit_cast(bf16x8, *(const u16x8*)&Pl[w][t * 72 + ks2 * 32 + 8 * g]);
#pragma unroll
      for (int db = 0; db < 8; ++db) {
        int coff = ((ks2 * 64 + 16 * g) ^ lx) >> 1;
        bf16x8 vf = __builtin_bit_cast(bf16x8, *(const u16x8*)&Vl[buf][(db * 16 + t) * 64 + coff]);
        oacc[db] = __builtin_amdgcn_mfma_f32_16x16x32_bf16(pf, vf, oacc[db], 0, 0, 0);
      }
    }
    __builtin_amdgcn_s_setprio(0);
    __syncthreads();                             // drains vmcnt: next buffer ready
    buf ^= 1;
  }
#pragma unroll
  for (int r = 0; r < 4; ++r) {
    float inv = 1.f / lrow[r];
    size_t orow = ((size_t)b * Ssz + qw + 4 * g + r) * (size_t)HIDsz + h * Dsz;
#pragma unroll
    for (int db = 0; db < 8; ++db)
      AO[orow + db * 16 + t] = f2bf(oacc[db][r] * inv);
  }
}

// ---------------- host ----------------
extern "C" void kernel_launch(void* const* d_in, const int* in_sizes, int n_in,
                              void* d_out, int out_size, void* d_ws, size_t ws_size,
                              hipStream_t stream) {
  (void)in_sizes; (void)n_in; (void)out_size;
  const float* hs   = (const float*)d_in[0];
  const int*   pos  = (const int*)d_in[1];
  const float* Wqkv = (const float*)d_in[2];
  const float* Wo   = (const float*)d_in[3];

  char* ws = (char*)d_ws;
  const size_t SZ_XBF = (size_t)4096 * 4096 * 2;   // also reused for AO
  const size_t SZ_WQ  = (size_t)6144 * 4096 * 2;
  const size_t SZ_WO  = (size_t)4096 * 4096 * 2;
  const size_t SZ_QKV = (size_t)4096 * 6144 * 2;
  const size_t SZ_QR  = (size_t)Bsz * Hsz * Ssz * Dsz * 2;
  const size_t SZ_KR  = (size_t)Bsz * KVsz * Ssz * Dsz * 2;
  const size_t SZ_VT  = SZ_KR;
  const size_t SZ_CS  = (size_t)Bsz * Ssz * 64 * 4;

  size_t off = 0;
  u16*   Xbf   = (u16*)(ws + off);  off += SZ_XBF;
  u16*   Wq_bf = (u16*)(ws + off);  off += SZ_WQ;
  u16*   Wo_bf = (u16*)(ws + off);  off += SZ_WO;
  u16*   qkv   = (u16*)(ws + off);  off += SZ_QKV;
  u16*   Qr    = (u16*)(ws + off);  off += SZ_QR;
  u16*   Kr    = (u16*)(ws + off);  off += SZ_KR;
  u16*   Vt    = (u16*)(ws + off);  off += SZ_VT;
  float* cosT  = (float*)(ws + off); off += SZ_CS;
  float* sinT  = (float*)(ws + off); off += SZ_CS;
  u16*   AO    = Xbf;                               // alias (Xbf dead after gemm1)
  if (ws_size < off) return;                        // fail loudly

  // 1. fp32 -> bf16 conversions
  k_cvt_bf16<<<(Bsz * Ssz * HIDsz) / 1024, 256, 0, stream>>>(hs, Xbf, (Bsz * Ssz * HIDsz) / 4);
  k_cvt_bf16<<<(NQKV * HIDsz) / 1024, 256, 0, stream>>>(Wqkv, Wq_bf, (NQKV * HIDsz) / 4);
  k_cvt_bf16<<<(HIDsz * HIDsz) / 1024, 256, 0, stream>>>(Wo, Wo_bf, (HIDsz * HIDsz) / 4);

  // 2. QKV projection: [4096,4096] x [6144,4096]^T -> [4096,6144]
  k_gemm<true><<<dim3(NQKV / 128, (Bsz * Ssz) / 128), 256, 0, stream>>>(Xbf, Wq_bf, qkv, Bsz * Ssz, NQKV, HIDsz);

  // 3. RoPE tables + apply + V transpose
  k_cs<<<(Bsz * Ssz * 64) / 256, 256, 0, stream>>>(pos, cosT, sinT);
  k_rope<<<(Bsz * Ssz * (Hsz + KVsz) * 64) / 256, 256, 0, stream>>>(qkv, cosT, sinT, Qr, Kr);
  k_vtrans<<<(Bsz * KVsz * Dsz * Ssz) / 256, 256, 0, stream>>>(qkv, Vt);

  // 4. causal GQA attention -> AO [B,S,H*D] bf16
  k_attn<<<dim3(Ssz / 64, Bsz * Hsz), 256, 0, stream>>>(Qr, Kr, Vt, AO);

  // 5. o_proj: [4096,4096] x [4096,4096]^T -> d_out fp32
  k_gemm<false><<<dim3(HIDsz / 128, (Bsz * Ssz) / 128), 256, 0, stream>>>(AO, Wo_bf, (float*)d_out, Bsz * Ssz, HIDsz, HIDsz);
}

// Round 3
// 822.908 us; speedup vs baseline: 1.3285x; 1.0889x over previous
//
#include <hip/hip_runtime.h>
#include <stdint.h>
#include <stddef.h>

#define Bsz   2
#define Ssz   2048
#define HIDsz 4096
#define Hsz   32
#define KVsz  8
#define Dsz   128
#define NQKV  6144                     // (H+2KV)*D
#define RSCALE 0.08838834764831845f    // 1/sqrt(128)

typedef __bf16 bf16x8 __attribute__((ext_vector_type(8)));
typedef float  f32x4  __attribute__((ext_vector_type(4)));
typedef unsigned short u16;
typedef u16 u16x4 __attribute__((ext_vector_type(4)));
typedef u16 u16x8 __attribute__((ext_vector_type(8)));

__device__ __forceinline__ u16 f2bf(float f) {
  uint32_t u = __builtin_bit_cast(uint32_t, f);
  u = (u + 0x7FFFu + ((u >> 16) & 1u)) >> 16;   // RNE
  return (u16)u;
}
__device__ __forceinline__ u16 f2bf_fast(float f) {  // round-half-up, 2 VALU
  uint32_t u = __builtin_bit_cast(uint32_t, f);
  return (u16)((u + 0x8000u) >> 16);
}
__device__ __forceinline__ float bf2f(u16 h) {
  return __builtin_bit_cast(float, (uint32_t)h << 16);
}

// global -> LDS async copy, 16B per lane; LDS dest = wave-uniform base + lane*16
#define GLDS(gp, lp) __builtin_amdgcn_global_load_lds( \
    (__attribute__((address_space(1))) void*)(void*)(gp), \
    (__attribute__((address_space(3))) void*)(lp), 16, 0, 0)

// ---------------- elementwise conversions ----------------
__global__ __launch_bounds__(256) void k_cvt_bf16(const float* __restrict__ in,
                                                  u16* __restrict__ out, int n4) {
  int i = blockIdx.x * 256 + threadIdx.x;
  if (i >= n4) return;
  float4 v = ((const float4*)in)[i];
  u16x4 o;
  o.x = f2bf(v.x); o.y = f2bf(v.y); o.z = f2bf(v.z); o.w = f2bf(v.w);
  ((u16x4*)out)[i] = o;
}

// cos/sin table [B*S][64]
__global__ __launch_bounds__(256) void k_cs(const int* __restrict__ pos,
                                            float* __restrict__ cosT,
                                            float* __restrict__ sinT) {
  int idx = blockIdx.x * 256 + threadIdx.x;       // B*S*64
  if (idx >= Bsz * Ssz * 64) return;
  int j = idx & 63;
  int bs = idx >> 6;
  float p = (float)pos[bs];
  float inv = __expf(-(float)j * (9.210340371976184f / 64.0f));
  float ang = p * inv;
  cosT[idx] = __cosf(ang);
  sinT[idx] = __sinf(ang);
}

// RoPE on q,k; q scaled by 1/sqrt(D); writes Qr[b][h][s][d], Kr[b][kvh][s][d]
__global__ __launch_bounds__(256) void k_rope(const u16* __restrict__ qkv,
                                              const float* __restrict__ cosT,
                                              const float* __restrict__ sinT,
                                              u16* __restrict__ Qr, u16* __restrict__ Kr) {
  int idx = blockIdx.x * 256 + threadIdx.x;       // B*S*(H+KV)*64
  if (idx >= Bsz * Ssz * (Hsz + KVsz) * 64) return;
  int j = idx & 63;
  int head = (idx >> 6) % (Hsz + KVsz);
  int bs = idx / (64 * (Hsz + KVsz));
  const u16* row = qkv + (size_t)bs * NQKV + head * Dsz;
  float x1 = bf2f(row[j]), x2 = bf2f(row[j + 64]);
  float c = cosT[bs * 64 + j], s = sinT[bs * 64 + j];
  float o1 = x1 * c - x2 * s;
  float o2 = x2 * c + x1 * s;
  int b = bs / Ssz, sidx = bs % Ssz;
  if (head < Hsz) {
    u16* o = Qr + ((size_t)(b * Hsz + head) * Ssz + sidx) * Dsz;
    o[j] = f2bf(o1 * RSCALE); o[j + 64] = f2bf(o2 * RSCALE);
  } else {
    int kvh = head - Hsz;
    u16* o = Kr + ((size_t)(b * KVsz + kvh) * Ssz + sidx) * Dsz;
    o[j] = f2bf(o1); o[j + 64] = f2bf(o2);
  }
}

// V transpose: Vt[b][kvh][d][s] = qkv[b,s, (H+KV)*D + kvh*D + d]
__global__ __launch_bounds__(256) void k_vtrans(const u16* __restrict__ qkv,
                                                u16* __restrict__ Vt) {
  int idx = blockIdx.x * 256 + threadIdx.x;       // B*KV*D*S
  if (idx >= Bsz * KVsz * Dsz * Ssz) return;
  int s = idx % Ssz;
  int rest = idx / Ssz;
  int d = rest % Dsz;
  int bk = rest / Dsz;
  int b = bk / KVsz, kvh = bk % KVsz;
  Vt[idx] = qkv[(size_t)(b * Ssz + s) * NQKV + (Hsz + KVsz) * Dsz + kvh * Dsz + d];
}

// ============ 256x256 8-phase GEMM: C[M][N] = A[M][K] * B[N][K]^T ============
// 512 threads = 8 waves (2 M x 4 N), per-wave 128x64 output, BK=64, 128KiB LDS.
// T2 XOR swizzle (both-sides), T3+T4 8-phase counted vmcnt(6), T5 setprio,
// T1 XCD-bijective block swizzle. Per phase: one C-quadrant (2 rowfrag x 4
// colfrag x 2 kk = 16 MFMA) + 1 half-tile stage (2 GLDS/thread).
// Half-tile h of A = rows {h*64..h*64+63} U {128+h*64..128+h*64+63} so it is
// exactly the rows consumed in quadrant-phases {2h+1, 2h+2}. B halves likewise
// (both B halves die in phase 1 of their K-tile since all B-frags load there).
// Stage schedule/iter: ph1:T1.A1 ph2:T2.B0 ph3:T2.B1 ph4:T2.A0+vmcnt(6)
//                      ph5:T2.A1 ph6:T3.B0 ph7:T3.A0 ph8:T3.B1+vmcnt(6)
// Every overwrite lands >=1 phase after the half's last read (reads complete at
// each phase's lgkmcnt(0) before barrier-B; stages issue after next barrier).

#define BARRIER_A  asm volatile("" ::: "memory"); __builtin_amdgcn_s_barrier(); \
                   asm volatile("s_waitcnt lgkmcnt(0)" ::: "memory"); \
                   __builtin_amdgcn_sched_barrier(0)
#define BARRIER_B  asm volatile("" ::: "memory"); __builtin_amdgcn_s_barrier()

#define PHASE(P_, Q_, STAGECODE, VMCODE) {                                     \
    bf16x8 a0 = LDA(P_, Q_, 0, 0), a1 = LDA(P_, Q_, 0, 1);                     \
    bf16x8 a2 = LDA(P_, Q_, 1, 0), a3 = LDA(P_, Q_, 1, 1);                     \
    if ((Q_) == 0) {                                                           \
      _Pragma("unroll") for (int nf = 0; nf < 4; ++nf) {                       \
        bfr[nf][0] = LDB(P_, nf, 0); bfr[nf][1] = LDB(P_, nf, 1); } }          \
    STAGECODE;                                                                 \
    VMCODE;                                                                    \
    BARRIER_A;                                                                 \
    __builtin_amdgcn_s_setprio(1);                                             \
    _Pragma("unroll") for (int nf = 0; nf < 4; ++nf) {                         \
      acc[(Q_)*2][nf]   = __builtin_amdgcn_mfma_f32_16x16x32_bf16(a0, bfr[nf][0], acc[(Q_)*2][nf],   0,0,0); \
      acc[(Q_)*2][nf]   = __builtin_amdgcn_mfma_f32_16x16x32_bf16(a1, bfr[nf][1], acc[(Q_)*2][nf],   0,0,0); \
      acc[(Q_)*2+1][nf] = __builtin_amdgcn_mfma_f32_16x16x32_bf16(a2, bfr[nf][0], acc[(Q_)*2+1][nf], 0,0,0); \
      acc[(Q_)*2+1][nf] = __builtin_amdgcn_mfma_f32_16x16x32_bf16(a3, bfr[nf][1], acc[(Q_)*2+1][nf], 0,0,0); \
    }                                                                          \
    __builtin_amdgcn_s_setprio(0);                                             \
    BARRIER_B;                                                                 \
  }

template <bool BF16OUT>
__global__ __launch_bounds__(512, 2) void k_gemm256(const u16* __restrict__ A,
                                                    const u16* __restrict__ Bm,
                                                    void* __restrict__ Cv,
                                                    int M, int N, int K) {
  __shared__ __align__(16) u16 SA[2][256 * 64];
  __shared__ __align__(16) u16 SB[2][256 * 64];
  const int tid = threadIdx.x;
  const int w = tid >> 6, lane = tid & 63;
  const int g = lane >> 4, t = lane & 15;
  const int wr = w >> 2, wc = w & 3;
  const int NB = N >> 8;
  const int cpx = gridDim.x >> 3;                 // grid %8 == 0 (384 / 256)
  const int swz = (blockIdx.x & 7) * cpx + (blockIdx.x >> 3);
  const int bm = swz / NB, bn = swz % NB;
  const int m0 = bm << 8, n0 = bn << 8;

  const char* Ab = (const char*)A;
  const char* Bb = (const char*)Bm;
  const size_t rowK = (size_t)K * 2;              // bytes per input row
  const int srcx = ((lane & 7) ^ (lane >> 3)) << 4;  // pre-swizzled src col
  const int l3 = lane >> 3;
  const int tx = (t & 7) << 4;                    // read-side XOR (bytes)

  auto SToff = [&](int h, int j) -> int {         // row base for inst j, half h
    int ii = w * 2 + j;
    return (ii < 8) ? (h * 64 + ii * 8) : (128 + h * 64 + (ii - 8) * 8);
  };
  auto STAGE_A = [&](int p, int T, int h) {
#pragma unroll
    for (int j = 0; j < 2; ++j) {
      int rb = SToff(h, j);
      GLDS(Ab + (size_t)(m0 + rb + l3) * rowK + (size_t)T * 128 + srcx,
           &SA[p][rb * 64]);
    }
  };
  auto STAGE_B = [&](int p, int T, int h) {
#pragma unroll
    for (int j = 0; j < 2; ++j) {
      int rb = SToff(h, j);
      GLDS(Bb + (size_t)(n0 + rb + l3) * rowK + (size_t)T * 128 + srcx,
           &SB[p][rb * 64]);
    }
  };
  auto LDA = [&](int p, int q, int fr, int kk) -> bf16x8 {
    int ar = wr * 128 + q * 32 + fr * 16 + t;
    const char* ptr = (const char*)&SA[p][0] + ar * 128 + ((kk * 64 + 16 * g) ^ tx);
    return __builtin_bit_cast(bf16x8, *(const u16x8*)ptr);
  };
  auto LDB = [&](int p, int nf, int kk) -> bf16x8 {
    int br = wc * 64 + nf * 16 + t;
    const char* ptr = (const char*)&SB[p][0] + br * 128 + ((kk * 64 + 16 * g) ^ tx);
    return __builtin_bit_cast(bf16x8, *(const u16x8*)ptr);
  };

  f32x4 acc[8][4];
#pragma unroll
  for (int i = 0; i < 8; ++i)
#pragma unroll
    for (int j = 0; j < 4; ++j) acc[i][j] = (f32x4){0.f, 0.f, 0.f, 0.f};
  bf16x8 bfr[4][2];

  // prologue: T0 complete (8 loads) + T1.{A0,B0,B1} (6 loads)
  STAGE_A(0, 0, 0); STAGE_B(0, 0, 0); STAGE_A(0, 0, 1); STAGE_B(0, 0, 1);
  STAGE_A(1, 1, 0); STAGE_B(1, 1, 0); STAGE_B(1, 1, 1);
  asm volatile("s_waitcnt vmcnt(6)" ::: "memory");   // T0 landed
  __builtin_amdgcn_s_barrier();

  const int NI = (K >> 7) - 1;                    // full iterations (2 K-tiles each)
  for (int i = 0; i < NI; ++i) {
    const int T1 = 2 * i + 1, T2 = 2 * i + 2, T3 = 2 * i + 3;
    PHASE(0, 0, STAGE_A(1, T1, 1), (void)0);
    PHASE(0, 1, STAGE_B(0, T2, 0), (void)0);
    PHASE(0, 2, STAGE_B(0, T2, 1), (void)0);
    PHASE(0, 3, STAGE_A(0, T2, 0), asm volatile("s_waitcnt vmcnt(6)" ::: "memory"));
    PHASE(1, 0, STAGE_A(0, T2, 1), (void)0);
    PHASE(1, 1, STAGE_B(1, T3, 0), (void)0);
    PHASE(1, 2, STAGE_A(1, T3, 0), (void)0);
    PHASE(1, 3, STAGE_B(1, T3, 1), asm volatile("s_waitcnt vmcnt(6)" ::: "memory"));
  }
  {                                               // peeled final iteration
    const int TL = (K >> 6) - 1;
    PHASE(0, 0, STAGE_A(1, TL, 1), (void)0);
    PHASE(0, 1, (void)0, (void)0);
    PHASE(0, 2, (void)0, (void)0);
    PHASE(0, 3, (void)0, asm volatile("s_waitcnt vmcnt(0)" ::: "memory"));
    PHASE(1, 0, (void)0, (void)0);
    PHASE(1, 1, (void)0, (void)0);
    PHASE(1, 2, (void)0, (void)0);
    PHASE(1, 3, (void)0, (void)0);
  }

  // epilogue: C-write (row = 4*(lane>>4)+reg, col = lane&15)
#pragma unroll
  for (int fi = 0; fi < 8; ++fi)
#pragma unroll
    for (int nf = 0; nf < 4; ++nf)
#pragma unroll
      for (int r = 0; r < 4; ++r) {
        int row = m0 + wr * 128 + fi * 16 + 4 * g + r;
        int col = n0 + wc * 64 + nf * 16 + t;
        float v = acc[fi][nf][r];
        if constexpr (BF16OUT) ((u16*)Cv)[(size_t)row * N + col] = f2bf(v);
        else                   ((float*)Cv)[(size_t)row * N + col] = v;
      }
}

// ---------------- flash attention (causal, GQA) ----------------
// grid (S/64, B*H); 4 waves, each wave owns 16 q-rows; KV tiles of 64.
__global__ __launch_bounds__(256) void k_attn(const u16* __restrict__ Qr,
                                              const u16* __restrict__ Kr,
                                              const u16* __restrict__ Vt,
                                              u16* __restrict__ AO) {
  __shared__ __align__(16) u16 Kl[2][64 * 128];  // [k][d], 256B rows, swizzled
  __shared__ __align__(16) u16 Vl[2][128 * 64];  // [d][k], 128B rows, swizzled
  __shared__ __align__(16) u16 Pl[4][16 * 72];   // per-wave P, padded stride 72
  const int tid = threadIdx.x;
  const int w = tid >> 6, lane = tid & 63;
  const int g = lane >> 4, t = lane & 15;
  const int bh = blockIdx.y;
  const int b = bh >> 5, h = bh & 31;
  const int kvh = h >> 2;                        // GQA: H/KV = 4
  const int bxr = gridDim.x - 1 - blockIdx.x;    // longest blocks dispatch first
  const int q0 = bxr * 64;
  const int qw = q0 + w * 16;
  const int ntiles = bxr + 1;
  const int lx = (t & 7) << 4;                   // read-side XOR (bytes)

  const u16* Qb = Qr + ((size_t)bh * Ssz + qw + t) * Dsz;
  bf16x8 qf[4];
#pragma unroll
  for (int ks = 0; ks < 4; ++ks)
    qf[ks] = __builtin_bit_cast(bf16x8, *(const u16x8*)(Qb + ks * 32 + 8 * g));

  f32x4 oacc[8];
#pragma unroll
  for (int db = 0; db < 8; ++db) oacc[db] = (f32x4){0.f, 0.f, 0.f, 0.f};
  float mrow[4] = {-1e30f, -1e30f, -1e30f, -1e30f};
  float lrow[4] = {0.f, 0.f, 0.f, 0.f};

  const char* Kbase = (const char*)(Kr + (size_t)(b * KVsz + kvh) * Ssz * Dsz);
  const char* Vbase = (const char*)(Vt + (size_t)(b * KVsz + kvh) * Dsz * Ssz);

  auto STAGE = [&](int bu, int kt2) {
    const int k0s = kt2 * 64;
#pragma unroll
    for (int i = 0; i < 4; ++i) {                // K: 4 rows (256B) per inst
      int rb = (w * 4 + i) * 4;
      int row = rb + (lane >> 4);
      int colb = ((lane & 15) * 16) ^ ((row & 7) << 4);
      GLDS(Kbase + ((size_t)(k0s + row) * 256 + colb), &Kl[bu][rb * 128]);
    }
#pragma unroll
    for (int i = 0; i < 4; ++i) {                // V: 8 rows (128B) per inst
      int rb = (w * 4 + i) * 8;
      int row = rb + (lane >> 3);
      int colb = ((lane & 7) * 16) ^ ((row & 7) << 4);
      GLDS(Vbase + ((size_t)row * (Ssz * 2) + (size_t)k0s * 2 + colb), &Vl[bu][rb * 64]);
    }
  };

  int buf = 0;
  STAGE(0, 0);
  __syncthreads();

  for (int kt = 0; kt < ntiles; ++kt) {
    const int k0 = kt * 64;
    if (kt + 1 < ntiles) STAGE(buf ^ 1, kt + 1);   // prefetch overlaps compute

    f32x4 sc[4];
    __builtin_amdgcn_s_setprio(1);
#pragma unroll
    for (int cb = 0; cb < 4; ++cb) {
      f32x4 a = (f32x4){0.f, 0.f, 0.f, 0.f};
#pragma unroll
      for (int ks = 0; ks < 4; ++ks) {
        int coff = ((ks * 64 + 16 * g) ^ lx) >> 1;
        bf16x8 kf = __builtin_bit_cast(bf16x8, *(const u16x8*)&Kl[buf][(cb * 16 + t) * 128 + coff]);
        a = __builtin_amdgcn_mfma_f32_16x16x32_bf16(qf[ks], kf, a, 0, 0, 0);
      }
      sc[cb] = a;
    }
    __builtin_amdgcn_s_setprio(0);

    const bool diag = (kt == ntiles - 1);
    float corr[4];
#pragma unroll
    for (int r = 0; r < 4; ++r) {
      int qg = qw + 4 * g + r;
      if (diag) {
#pragma unroll
        for (int cb = 0; cb < 4; ++cb) {
          int kg = k0 + cb * 16 + t;
          if (kg > qg) sc[cb][r] = -1e30f;
        }
      }
      float tm = fmaxf(fmaxf(sc[0][r], sc[1][r]), fmaxf(sc[2][r], sc[3][r]));
#pragma unroll
      for (int m = 1; m < 16; m <<= 1) tm = fmaxf(tm, __shfl_xor(tm, m, 64));
      float mnew = fmaxf(mrow[r], tm);
      corr[r] = __expf(mrow[r] - mnew);
      float ps = 0.f;
#pragma unroll
      for (int cb = 0; cb < 4; ++cb) {
        float p = __expf(sc[cb][r] - mnew);
        sc[cb][r] = p; ps += p;
      }
#pragma unroll
      for (int m = 1; m < 16; m <<= 1) ps += __shfl_xor(ps, m, 64);
      lrow[r] = lrow[r] * corr[r] + ps;
      mrow[r] = mnew;
    }
#pragma unroll
    for (int db = 0; db < 8; ++db) {
      f32x4 o = oacc[db];
      o[0] *= corr[0]; o[1] *= corr[1]; o[2] *= corr[2]; o[3] *= corr[3];
      oacc[db] = o;
    }
#pragma unroll
    for (int r = 0; r < 4; ++r)
#pragma unroll
      for (int cb = 0; cb < 4; ++cb)
        Pl[w][(4 * g + r) * 72 + cb * 16 + t] = f2bf_fast(sc[cb][r]);
    asm volatile("s_waitcnt lgkmcnt(0)" ::: "memory");   // DS in-order: writes done
    __builtin_amdgcn_s_setprio(1);
#pragma unroll
    for (int ks2 = 0; ks2 < 2; ++ks2) {
      bf16x8 pf = __builtin_bit_cast(bf16x8, *(const u16x8*)&Pl[w][t * 72 + ks2 * 32 + 8 * g]);
#pragma unroll
      for (int db = 0; db < 8; ++db) {
        int coff = ((ks2 * 64 + 16 * g) ^ lx) >> 1;
        bf16x8 vf = __builtin_bit_cast(bf16x8, *(const u16x8*)&Vl[buf][(db * 16 + t) * 64 + coff]);
        oacc[db] = __builtin_amdgcn_mfma_f32_16x16x32_bf16(pf, vf, oacc[db], 0, 0, 0);
      }
    }
    __builtin_amdgcn_s_setprio(0);
    __syncthreads();                             // drains vmcnt: next buffer ready
    buf ^= 1;
  }
#pragma unroll
  for (int r = 0; r < 4; ++r) {
    float inv = 1.f / lrow[r];
    size_t orow = ((size_t)b * Ssz + qw + 4 * g + r) * (size_t)HIDsz + h * Dsz;
#pragma unroll
    for (int db = 0; db < 8; ++db)
      AO[orow + db * 16 + t] = f2bf(oacc[db][r] * inv);
  }
}

// ---------------- host ----------------
extern "C" void kernel_launch(void* const* d_in, const int* in_sizes, int n_in,
                              void* d_out, int out_size, void* d_ws, size_t ws_size,
                              hipStream_t stream) {
  (void)in_sizes; (void)n_in; (void)out_size;
  const float* hs   = (const float*)d_in[0];
  const int*   pos  = (const int*)d_in[1];
  const float* Wqkv = (const float*)d_in[2];
  const float* Wo   = (const float*)d_in[3];

  char* ws = (char*)d_ws;
  const size_t SZ_XBF = (size_t)4096 * 4096 * 2;   // also reused for AO
  const size_t SZ_WQ  = (size_t)6144 * 4096 * 2;
  const size_t SZ_WO  = (size_t)4096 * 4096 * 2;
  const size_t SZ_QKV = (size_t)4096 * 6144 * 2;
  const size_t SZ_QR  = (size_t)Bsz * Hsz * Ssz * Dsz * 2;
  const size_t SZ_KR  = (size_t)Bsz * KVsz * Ssz * Dsz * 2;
  const size_t SZ_VT  = SZ_KR;
  const size_t SZ_CS  = (size_t)Bsz * Ssz * 64 * 4;

  size_t off = 0;
  u16*   Xbf   = (u16*)(ws + off);  off += SZ_XBF;
  u16*   Wq_bf = (u16*)(ws + off);  off += SZ_WQ;
  u16*   Wo_bf = (u16*)(ws + off);  off += SZ_WO;
  u16*   qkv   = (u16*)(ws + off);  off += SZ_QKV;
  u16*   Qr    = (u16*)(ws + off);  off += SZ_QR;
  u16*   Kr    = (u16*)(ws + off);  off += SZ_KR;
  u16*   Vt    = (u16*)(ws + off);  off += SZ_VT;
  float* cosT  = (float*)(ws + off); off += SZ_CS;
  float* sinT  = (float*)(ws + off); off += SZ_CS;
  u16*   AO    = Xbf;                               // alias (Xbf dead after gemm1)
  if (ws_size < off) return;                        // fail loudly

  // 1. fp32 -> bf16 conversions
  k_cvt_bf16<<<(Bsz * Ssz * HIDsz) / 1024, 256, 0, stream>>>(hs, Xbf, (Bsz * Ssz * HIDsz) / 4);
  k_cvt_bf16<<<(NQKV * HIDsz) / 1024, 256, 0, stream>>>(Wqkv, Wq_bf, (NQKV * HIDsz) / 4);
  k_cvt_bf16<<<(HIDsz * HIDsz) / 1024, 256, 0, stream>>>(Wo, Wo_bf, (HIDsz * HIDsz) / 4);

  // 2. QKV projection: [4096,4096] x [6144,4096]^T -> [4096,6144]
  k_gemm256<true><<<dim3((NQKV / 256) * ((Bsz * Ssz) / 256)), 512, 0, stream>>>(
      Xbf, Wq_bf, qkv, Bsz * Ssz, NQKV, HIDsz);

  // 3. RoPE tables + apply + V transpose
  k_cs<<<(Bsz * Ssz * 64) / 256, 256, 0, stream>>>(pos, cosT, sinT);
  k_rope<<<(Bsz * Ssz * (Hsz + KVsz) * 64) / 256, 256, 0, stream>>>(qkv, cosT, sinT, Qr, Kr);
  k_vtrans<<<(Bsz * KVsz * Dsz * Ssz) / 256, 256, 0, stream>>>(qkv, Vt);

  // 4. causal GQA attention -> AO [B,S,H*D] bf16
  k_attn<<<dim3(Ssz / 64, Bsz * Hsz), 256, 0, stream>>>(Qr, Kr, Vt, AO);

  // 5. o_proj: [4096,4096] x [4096,4096]^T -> d_out fp32
  k_gemm256<false><<<dim3((HIDsz / 256) * ((Bsz * Ssz) / 256)), 512, 0, stream>>>(
      AO, Wo_bf, (float*)d_out, Bsz * Ssz, HIDsz, HIDsz);
}

// Round 4
// 703.928 us; speedup vs baseline: 1.5531x; 1.1690x over previous
//
#include <hip/hip_runtime.h>
#include <stdint.h>
#include <stddef.h>

#define Bsz   2
#define Ssz   2048
#define HIDsz 4096
#define Hsz   32
#define KVsz  8
#define Dsz   128
#define NQKV  6144                     // (H+2KV)*D
#define RSCALE 0.08838834764831845f    // 1/sqrt(128)

typedef __bf16 bf16x8 __attribute__((ext_vector_type(8)));
typedef float  f32x4  __attribute__((ext_vector_type(4)));
typedef float  f32x16 __attribute__((ext_vector_type(16)));
typedef unsigned short u16;
typedef u16 u16x4 __attribute__((ext_vector_type(4)));
typedef u16 u16x8 __attribute__((ext_vector_type(8)));
typedef uint32_t u32x4 __attribute__((ext_vector_type(4)));

__device__ __forceinline__ u16 f2bf(float f) {
  uint32_t u = __builtin_bit_cast(uint32_t, f);
  u = (u + 0x7FFFu + ((u >> 16) & 1u)) >> 16;   // RNE
  return (u16)u;
}
__device__ __forceinline__ u16 f2bf_fast(float f) {  // round-half-up, 2 VALU
  uint32_t u = __builtin_bit_cast(uint32_t, f);
  return (u16)((u + 0x8000u) >> 16);
}
__device__ __forceinline__ float bf2f(u16 h) {
  return __builtin_bit_cast(float, (uint32_t)h << 16);
}
__device__ __forceinline__ uint32_t packbf2(float lo, float hi_) {
  return (uint32_t)f2bf_fast(lo) | ((uint32_t)f2bf_fast(hi_) << 16);
}

// global -> LDS async copy, 16B per lane; LDS dest = wave-uniform base + lane*16
#define GLDS(gp, lp) __builtin_amdgcn_global_load_lds( \
    (__attribute__((address_space(1))) void*)(void*)(gp), \
    (__attribute__((address_space(3))) void*)(lp), 16, 0, 0)

// ---------------- elementwise conversions ----------------
__global__ __launch_bounds__(256) void k_cvt_bf16(const float* __restrict__ in,
                                                  u16* __restrict__ out, int n4) {
  int i = blockIdx.x * 256 + threadIdx.x;
  if (i >= n4) return;
  float4 v = ((const float4*)in)[i];
  u16x4 o;
  o.x = f2bf(v.x); o.y = f2bf(v.y); o.z = f2bf(v.z); o.w = f2bf(v.w);
  ((u16x4*)out)[i] = o;
}

// cos/sin table [B*S][64]
__global__ __launch_bounds__(256) void k_cs(const int* __restrict__ pos,
                                            float* __restrict__ cosT,
                                            float* __restrict__ sinT) {
  int idx = blockIdx.x * 256 + threadIdx.x;       // B*S*64
  if (idx >= Bsz * Ssz * 64) return;
  int j = idx & 63;
  int bs = idx >> 6;
  float p = (float)pos[bs];
  float inv = __expf(-(float)j * (9.210340371976184f / 64.0f));
  float ang = p * inv;
  cosT[idx] = __cosf(ang);
  sinT[idx] = __sinf(ang);
}

// RoPE on q,k; q scaled by 1/sqrt(D); writes Qr[b][h][s][d], Kr[b][kvh][s][d]
__global__ __launch_bounds__(256) void k_rope(const u16* __restrict__ qkv,
                                              const float* __restrict__ cosT,
                                              const float* __restrict__ sinT,
                                              u16* __restrict__ Qr, u16* __restrict__ Kr) {
  int idx = blockIdx.x * 256 + threadIdx.x;       // B*S*(H+KV)*64
  if (idx >= Bsz * Ssz * (Hsz + KVsz) * 64) return;
  int j = idx & 63;
  int head = (idx >> 6) % (Hsz + KVsz);
  int bs = idx / (64 * (Hsz + KVsz));
  const u16* row = qkv + (size_t)bs * NQKV + head * Dsz;
  float x1 = bf2f(row[j]), x2 = bf2f(row[j + 64]);
  float c = cosT[bs * 64 + j], s = sinT[bs * 64 + j];
  float o1 = x1 * c - x2 * s;
  float o2 = x2 * c + x1 * s;
  int b = bs / Ssz, sidx = bs % Ssz;
  if (head < Hsz) {
    u16* o = Qr + ((size_t)(b * Hsz + head) * Ssz + sidx) * Dsz;
    o[j] = f2bf(o1 * RSCALE); o[j + 64] = f2bf(o2 * RSCALE);
  } else {
    int kvh = head - Hsz;
    u16* o = Kr + ((size_t)(b * KVsz + kvh) * Ssz + sidx) * Dsz;
    o[j] = f2bf(o1); o[j + 64] = f2bf(o2);
  }
}

// V transpose, LDS-tiled: Vt[b][kvh][d][s] = qkv[b,s, (H+KV)*D + kvh*D + d]
// 64x64 tiles; Tl rows padded to 144B; 16B chunks placed at chunk^(s>>3) so
// phase-2 column gathers spread banks (2-way max).
__global__ __launch_bounds__(256) void k_vtrans(const u16* __restrict__ qkv,
                                                u16* __restrict__ Vt) {
  __shared__ __align__(16) u16 Tl[64 * 72];
  const int tid = threadIdx.x;
  const int bk = blockIdx.y;                      // b*KV + kvh
  const int s0 = (blockIdx.x >> 1) * 64;
  const int d0 = (blockIdx.x & 1) * 64;
  const int b = bk >> 3, kvh = bk & 7;
  const u16* src = qkv + (size_t)(b * Ssz + s0) * NQKV + (Hsz + KVsz) * Dsz + kvh * Dsz + d0;
#pragma unroll
  for (int p = 0; p < 2; ++p) {
    int cid = p * 256 + tid;
    int r = cid >> 3, co = cid & 7;
    int chunk = co ^ ((r >> 3) & 7);
    *(u16x8*)((char*)Tl + r * 144 + chunk * 16) =
        *(const u16x8*)(src + (size_t)r * NQKV + co * 8);
  }
  __syncthreads();
#pragma unroll
  for (int p = 0; p < 2; ++p) {
    int cid = p * 256 + tid;
    int dr = cid >> 3, c = cid & 7;
    u16x8 v;
#pragma unroll
    for (int j = 0; j < 8; ++j) {
      int s = 8 * c + j;
      v[j] = *(const u16*)((char*)Tl + s * 144 + (((dr >> 3) ^ c) * 16) + (dr & 7) * 2);
    }
    *(u16x8*)(Vt + ((size_t)bk * Dsz + d0 + dr) * Ssz + s0 + 8 * c) = v;
  }
}

// ============ 256x256 8-phase GEMM: C[M][N] = A[M][K] * B[N][K]^T ============
#define BARRIER_A  asm volatile("" ::: "memory"); __builtin_amdgcn_s_barrier(); \
                   asm volatile("s_waitcnt lgkmcnt(0)" ::: "memory"); \
                   __builtin_amdgcn_sched_barrier(0)
#define BARRIER_B  asm volatile("" ::: "memory"); __builtin_amdgcn_s_barrier()

#define PHASE(P_, Q_, STAGECODE, VMCODE) {                                     \
    bf16x8 a0 = LDA(P_, Q_, 0, 0), a1 = LDA(P_, Q_, 0, 1);                     \
    bf16x8 a2 = LDA(P_, Q_, 1, 0), a3 = LDA(P_, Q_, 1, 1);                     \
    if ((Q_) == 0) {                                                           \
      _Pragma("unroll") for (int nf = 0; nf < 4; ++nf) {                       \
        bfr[nf][0] = LDB(P_, nf, 0); bfr[nf][1] = LDB(P_, nf, 1); } }          \
    STAGECODE;                                                                 \
    VMCODE;                                                                    \
    BARRIER_A;                                                                 \
    __builtin_amdgcn_s_setprio(1);                                             \
    _Pragma("unroll") for (int nf = 0; nf < 4; ++nf) {                         \
      acc[(Q_)*2][nf]   = __builtin_amdgcn_mfma_f32_16x16x32_bf16(a0, bfr[nf][0], acc[(Q_)*2][nf],   0,0,0); \
      acc[(Q_)*2][nf]   = __builtin_amdgcn_mfma_f32_16x16x32_bf16(a1, bfr[nf][1], acc[(Q_)*2][nf],   0,0,0); \
      acc[(Q_)*2+1][nf] = __builtin_amdgcn_mfma_f32_16x16x32_bf16(a2, bfr[nf][0], acc[(Q_)*2+1][nf], 0,0,0); \
      acc[(Q_)*2+1][nf] = __builtin_amdgcn_mfma_f32_16x16x32_bf16(a3, bfr[nf][1], acc[(Q_)*2+1][nf], 0,0,0); \
    }                                                                          \
    __builtin_amdgcn_s_setprio(0);                                             \
    BARRIER_B;                                                                 \
  }

template <bool BF16OUT>
__global__ __launch_bounds__(512, 2) void k_gemm256(const u16* __restrict__ A,
                                                    const u16* __restrict__ Bm,
                                                    void* __restrict__ Cv,
                                                    int M, int N, int K) {
  __shared__ __align__(16) u16 SA[2][256 * 64];
  __shared__ __align__(16) u16 SB[2][256 * 64];
  const int tid = threadIdx.x;
  const int w = tid >> 6, lane = tid & 63;
  const int g = lane >> 4, t = lane & 15;
  const int wr = w >> 2, wc = w & 3;
  const int NB = N >> 8;
  const int cpx = gridDim.x >> 3;                 // grid %8 == 0 (384 / 256)
  const int swz = (blockIdx.x & 7) * cpx + (blockIdx.x >> 3);
  const int bm = swz / NB, bn = swz % NB;
  const int m0 = bm << 8, n0 = bn << 8;

  const char* Ab = (const char*)A;
  const char* Bb = (const char*)Bm;
  const size_t rowK = (size_t)K * 2;              // bytes per input row
  const int srcx = ((lane & 7) ^ (lane >> 3)) << 4;  // pre-swizzled src col
  const int l3 = lane >> 3;
  const int tx = (t & 7) << 4;                    // read-side XOR (bytes)

  auto SToff = [&](int h, int j) -> int {
    int ii = w * 2 + j;
    return (ii < 8) ? (h * 64 + ii * 8) : (128 + h * 64 + (ii - 8) * 8);
  };
  auto STAGE_A = [&](int p, int T, int h) {
#pragma unroll
    for (int j = 0; j < 2; ++j) {
      int rb = SToff(h, j);
      GLDS(Ab + (size_t)(m0 + rb + l3) * rowK + (size_t)T * 128 + srcx,
           &SA[p][rb * 64]);
    }
  };
  auto STAGE_B = [&](int p, int T, int h) {
#pragma unroll
    for (int j = 0; j < 2; ++j) {
      int rb = SToff(h, j);
      GLDS(Bb + (size_t)(n0 + rb + l3) * rowK + (size_t)T * 128 + srcx,
           &SB[p][rb * 64]);
    }
  };
  auto LDA = [&](int p, int q, int fr, int kk) -> bf16x8 {
    int ar = wr * 128 + q * 32 + fr * 16 + t;
    const char* ptr = (const char*)&SA[p][0] + ar * 128 + ((kk * 64 + 16 * g) ^ tx);
    return __builtin_bit_cast(bf16x8, *(const u16x8*)ptr);
  };
  auto LDB = [&](int p, int nf, int kk) -> bf16x8 {
    int br = wc * 64 + nf * 16 + t;
    const char* ptr = (const char*)&SB[p][0] + br * 128 + ((kk * 64 + 16 * g) ^ tx);
    return __builtin_bit_cast(bf16x8, *(const u16x8*)ptr);
  };

  f32x4 acc[8][4];
#pragma unroll
  for (int i = 0; i < 8; ++i)
#pragma unroll
    for (int j = 0; j < 4; ++j) acc[i][j] = (f32x4){0.f, 0.f, 0.f, 0.f};
  bf16x8 bfr[4][2];

  STAGE_A(0, 0, 0); STAGE_B(0, 0, 0); STAGE_A(0, 0, 1); STAGE_B(0, 0, 1);
  STAGE_A(1, 1, 0); STAGE_B(1, 1, 0); STAGE_B(1, 1, 1);
  asm volatile("s_waitcnt vmcnt(6)" ::: "memory");   // T0 landed
  __builtin_amdgcn_s_barrier();

  const int NI = (K >> 7) - 1;
  for (int i = 0; i < NI; ++i) {
    const int T1 = 2 * i + 1, T2 = 2 * i + 2, T3 = 2 * i + 3;
    PHASE(0, 0, STAGE_A(1, T1, 1), (void)0);
    PHASE(0, 1, STAGE_B(0, T2, 0), (void)0);
    PHASE(0, 2, STAGE_B(0, T2, 1), (void)0);
    PHASE(0, 3, STAGE_A(0, T2, 0), asm volatile("s_waitcnt vmcnt(6)" ::: "memory"));
    PHASE(1, 0, STAGE_A(0, T2, 1), (void)0);
    PHASE(1, 1, STAGE_B(1, T3, 0), (void)0);
    PHASE(1, 2, STAGE_A(1, T3, 0), (void)0);
    PHASE(1, 3, STAGE_B(1, T3, 1), asm volatile("s_waitcnt vmcnt(6)" ::: "memory"));
  }
  {
    const int TL = (K >> 6) - 1;
    PHASE(0, 0, STAGE_A(1, TL, 1), (void)0);
    PHASE(0, 1, (void)0, (void)0);
    PHASE(0, 2, (void)0, (void)0);
    PHASE(0, 3, (void)0, asm volatile("s_waitcnt vmcnt(0)" ::: "memory"));
    PHASE(1, 0, (void)0, (void)0);
    PHASE(1, 1, (void)0, (void)0);
    PHASE(1, 2, (void)0, (void)0);
    PHASE(1, 3, (void)0, (void)0);
  }

#pragma unroll
  for (int fi = 0; fi < 8; ++fi)
#pragma unroll
    for (int nf = 0; nf < 4; ++nf)
#pragma unroll
      for (int r = 0; r < 4; ++r) {
        int row = m0 + wr * 128 + fi * 16 + 4 * g + r;
        int col = n0 + wc * 64 + nf * 16 + t;
        float v = acc[fi][nf][r];
        if constexpr (BF16OUT) ((u16*)Cv)[(size_t)row * N + col] = f2bf(v);
        else                   ((float*)Cv)[(size_t)row * N + col] = v;
      }
}

// ---------------- flash attention: 8-wave swapped-QK^T 32x32 ----------------
// grid (S/256, B*H), 512 threads. Wave w owns q-rows qw..qw+31. Per KV tile 64:
//   QK^T = mfma32(K_frag, Q_frag) -> D[k][q]: q = lane&31 (lane-local row!)
//   softmax: in-lane over 32 regs + one shfl_xor(32) with partner lane
//   P kept in-register: pack bf16 pairs, 16 shfl_xor(32) word exchange
//   PV = mfma32(Vt_frag, P_frag) -> D[d][q]: rescale/normalize lane-local
__global__ __launch_bounds__(512, 2) void k_attn(const u16* __restrict__ Qr,
                                                 const u16* __restrict__ Kr,
                                                 const u16* __restrict__ Vt,
                                                 u16* __restrict__ AO) {
  __shared__ __align__(16) u16 Kl[2][64 * 128];  // [k][d] swizzled
  __shared__ __align__(16) u16 Vl[2][128 * 64];  // [d][k] swizzled
  const int tid = threadIdx.x;
  const int w = tid >> 6, lane = tid & 63;
  const int q = lane & 31, hi = lane >> 5;
  const int bh = blockIdx.y;
  const int b = bh >> 5, h = bh & 31;
  const int kvh = h >> 2;                        // GQA: H/KV = 4
  const int bxr = gridDim.x - 1 - blockIdx.x;    // longest blocks first
  const int q0 = bxr * 256;
  const int qw = q0 + w * 32;
  const int ntiles = 4 * bxr + 4;
  const int qg = qw + q;

  // Q frags: lane gives Q[qw+q][16*ds + 8*hi + jj]
  const u16* Qb = Qr + ((size_t)bh * Ssz + qw + q) * Dsz + hi * 8;
  bf16x8 qf[8];
#pragma unroll
  for (int ds = 0; ds < 8; ++ds)
    qf[ds] = __builtin_bit_cast(bf16x8, *(const u16x8*)(Qb + ds * 16));

  f32x16 oacc[4];
#pragma unroll
  for (int dt = 0; dt < 4; ++dt)
#pragma unroll
    for (int r = 0; r < 16; ++r) oacc[dt][r] = 0.f;
  float mr = -1e30f, lr = 0.f;

  const char* Kbase = (const char*)(Kr + (size_t)(b * KVsz + kvh) * Ssz * Dsz);
  const char* Vbase = (const char*)(Vt + (size_t)(b * KVsz + kvh) * Dsz * Ssz);

  auto STAGE = [&](int bu, int kt2) {
    const char* Kb = Kbase + (size_t)kt2 * (64 * 256);
    const char* Vb = Vbase + (size_t)kt2 * 128;   // 64 cols * 2B
#pragma unroll
    for (int j = 0; j < 2; ++j) {
      int flat = j * 512 + tid;
      int row = flat >> 4, colb = ((flat & 15) * 16) ^ ((row & 7) << 4);
      GLDS(Kb + (size_t)row * 256 + colb, (char*)&Kl[bu][0] + flat * 16);
    }
#pragma unroll
    for (int j = 0; j < 2; ++j) {
      int flat = j * 512 + tid;
      int row = flat >> 3, colb = ((flat & 7) * 16) ^ ((row & 7) << 4);
      GLDS(Vb + (size_t)row * (Ssz * 2) + colb, (char*)&Vl[bu][0] + flat * 16);
    }
  };

  int buf = 0;
  STAGE(0, 0);
  __syncthreads();

  for (int kt = 0; kt < ntiles; ++kt) {
    const int k0 = kt * 64;
    if (kt + 1 < ntiles) STAGE(buf ^ 1, kt + 1);   // prefetch overlaps compute

    if (k0 <= qw + 31) {                           // wave participates
      f32x16 pa0, pa1;
#pragma unroll
      for (int r = 0; r < 16; ++r) { pa0[r] = 0.f; pa1[r] = 0.f; }
      __builtin_amdgcn_s_setprio(1);
#pragma unroll
      for (int ds = 0; ds < 8; ++ds) {
        {
          const int row = q;
          const char* kp = (const char*)&Kl[buf][0] + row * 256 +
                           ((ds * 32 + hi * 16) ^ ((row & 7) << 4));
          bf16x8 kf = __builtin_bit_cast(bf16x8, *(const u16x8*)kp);
          pa0 = __builtin_amdgcn_mfma_f32_32x32x16_bf16(kf, qf[ds], pa0, 0, 0, 0);
        }
        {
          const int row = 32 + q;
          const char* kp = (const char*)&Kl[buf][0] + row * 256 +
                           ((ds * 32 + hi * 16) ^ ((row & 7) << 4));
          bf16x8 kf = __builtin_bit_cast(bf16x8, *(const u16x8*)kp);
          pa1 = __builtin_amdgcn_mfma_f32_32x32x16_bf16(kf, qf[ds], pa1, 0, 0, 0);
        }
      }
      __builtin_amdgcn_s_setprio(0);

      // causal mask: k index of pa?[reg] = k0 (+32) + (reg&3)+8*(reg>>2)+4*hi
      if (k0 + 63 > qw) {
#pragma unroll
        for (int reg = 0; reg < 16; ++reg) {
          const int kb = (reg & 3) + 8 * (reg >> 2) + 4 * hi;
          if (k0 + kb > qg)      pa0[reg] = -1e30f;
          if (k0 + 32 + kb > qg) pa1[reg] = -1e30f;
        }
      }
      // online softmax, lane-local (partner lane^32 holds other half of row)
      float mx = -1e30f;
#pragma unroll
      for (int reg = 0; reg < 16; ++reg) mx = fmaxf(mx, fmaxf(pa0[reg], pa1[reg]));
      mx = fmaxf(mx, __shfl_xor(mx, 32, 64));
      const float mnew = fmaxf(mr, mx);
      const float corr = __expf(mr - mnew);
      float ps = 0.f;
#pragma unroll
      for (int reg = 0; reg < 16; ++reg) {
        pa0[reg] = __expf(pa0[reg] - mnew);
        pa1[reg] = __expf(pa1[reg] - mnew);
        ps += pa0[reg] + pa1[reg];
      }
      ps += __shfl_xor(ps, 32, 64);
      lr = lr * corr + ps;
      mr = mnew;
#pragma unroll
      for (int dt = 0; dt < 4; ++dt)
#pragma unroll
        for (int reg = 0; reg < 16; ++reg) oacc[dt][reg] *= corr;

      // pack P pairs -> words W[T][r2][c] (k = 8*r2 + 4*hi + 2*c + 32*T)
      uint32_t W[2][4][2], X[2][4][2];
#pragma unroll
      for (int r2 = 0; r2 < 4; ++r2)
#pragma unroll
        for (int c = 0; c < 2; ++c) {
          W[0][r2][c] = packbf2(pa0[4 * r2 + 2 * c], pa0[4 * r2 + 2 * c + 1]);
          W[1][r2][c] = packbf2(pa1[4 * r2 + 2 * c], pa1[4 * r2 + 2 * c + 1]);
        }
#pragma unroll
      for (int T = 0; T < 2; ++T)
#pragma unroll
        for (int r2 = 0; r2 < 4; ++r2)
#pragma unroll
          for (int c = 0; c < 2; ++c)
            X[T][r2][c] = __shfl_xor(W[T][r2][c], 32, 64);

      // PV: b-frag = P[q][16ks+8hi .. +7], a-frag = Vt rows
      __builtin_amdgcn_s_setprio(1);
#pragma unroll
      for (int ks = 0; ks < 4; ++ks) {
        const int T = ks >> 1, r2e = 2 * (ks & 1);
        u32x4 fw;
        fw[0] = hi ? X[T][r2e + 1][0] : W[T][r2e][0];
        fw[1] = hi ? X[T][r2e + 1][1] : W[T][r2e][1];
        fw[2] = hi ? W[T][r2e + 1][0] : X[T][r2e][0];
        fw[3] = hi ? W[T][r2e + 1][1] : X[T][r2e][1];
        bf16x8 pf = __builtin_bit_cast(bf16x8, fw);
#pragma unroll
        for (int dt = 0; dt < 4; ++dt) {
          const int row = dt * 32 + q;
          const char* vp = (const char*)&Vl[buf][0] + row * 128 +
                           ((ks * 32 + hi * 16) ^ ((row & 7) << 4));
          bf16x8 vf = __builtin_bit_cast(bf16x8, *(const u16x8*)vp);
          oacc[dt] = __builtin_amdgcn_mfma_f32_32x32x16_bf16(vf, pf, oacc[dt], 0, 0, 0);
        }
      }
      __builtin_amdgcn_s_setprio(0);
    }
    __syncthreads();                             // drains vmcnt: next buffer ready
    buf ^= 1;
  }

  // epilogue: O[q][d], d = dt*32 + 8*r2 + 4*hi + j
  const float inv = 1.f / lr;
  u16* Ob = AO + ((size_t)(b * Ssz) + qw + q) * HIDsz + h * Dsz + hi * 4;
#pragma unroll
  for (int dt = 0; dt < 4; ++dt)
#pragma unroll
    for (int r2 = 0; r2 < 4; ++r2) {
      u16x4 o4;
#pragma unroll
      for (int j = 0; j < 4; ++j) o4[j] = f2bf(oacc[dt][4 * r2 + j] * inv);
      *(u16x4*)(Ob + dt * 32 + r2 * 8) = o4;
    }
}

// ---------------- host ----------------
extern "C" void kernel_launch(void* const* d_in, const int* in_sizes, int n_in,
                              void* d_out, int out_size, void* d_ws, size_t ws_size,
                              hipStream_t stream) {
  (void)in_sizes; (void)n_in; (void)out_size;
  const float* hs   = (const float*)d_in[0];
  const int*   pos  = (const int*)d_in[1];
  const float* Wqkv = (const float*)d_in[2];
  const float* Wo   = (const float*)d_in[3];

  char* ws = (char*)d_ws;
  const size_t SZ_XBF = (size_t)4096 * 4096 * 2;   // also reused for AO
  const size_t SZ_WQ  = (size_t)6144 * 4096 * 2;
  const size_t SZ_WO  = (size_t)4096 * 4096 * 2;
  const size_t SZ_QKV = (size_t)4096 * 6144 * 2;
  const size_t SZ_QR  = (size_t)Bsz * Hsz * Ssz * Dsz * 2;
  const size_t SZ_KR  = (size_t)Bsz * KVsz * Ssz * Dsz * 2;
  const size_t SZ_VT  = SZ_KR;
  const size_t SZ_CS  = (size_t)Bsz * Ssz * 64 * 4;

  size_t off = 0;
  u16*   Xbf   = (u16*)(ws + off);  off += SZ_XBF;
  u16*   Wq_bf = (u16*)(ws + off);  off += SZ_WQ;
  u16*   Wo_bf = (u16*)(ws + off);  off += SZ_WO;
  u16*   qkv   = (u16*)(ws + off);  off += SZ_QKV;
  u16*   Qr    = (u16*)(ws + off);  off += SZ_QR;
  u16*   Kr    = (u16*)(ws + off);  off += SZ_KR;
  u16*   Vt    = (u16*)(ws + off);  off += SZ_VT;
  float* cosT  = (float*)(ws + off); off += SZ_CS;
  float* sinT  = (float*)(ws + off); off += SZ_CS;
  u16*   AO    = Xbf;                               // alias (Xbf dead after gemm1)
  if (ws_size < off) return;                        // fail loudly

  // 1. fp32 -> bf16 conversions
  k_cvt_bf16<<<(Bsz * Ssz * HIDsz) / 1024, 256, 0, stream>>>(hs, Xbf, (Bsz * Ssz * HIDsz) / 4);
  k_cvt_bf16<<<(NQKV * HIDsz) / 1024, 256, 0, stream>>>(Wqkv, Wq_bf, (NQKV * HIDsz) / 4);
  k_cvt_bf16<<<(HIDsz * HIDsz) / 1024, 256, 0, stream>>>(Wo, Wo_bf, (HIDsz * HIDsz) / 4);

  // 2. QKV projection: [4096,4096] x [6144,4096]^T -> [4096,6144]
  k_gemm256<true><<<dim3((NQKV / 256) * ((Bsz * Ssz) / 256)), 512, 0, stream>>>(
      Xbf, Wq_bf, qkv, Bsz * Ssz, NQKV, HIDsz);

  // 3. RoPE tables + apply + V transpose
  k_cs<<<(Bsz * Ssz * 64) / 256, 256, 0, stream>>>(pos, cosT, sinT);
  k_rope<<<(Bsz * Ssz * (Hsz + KVsz) * 64) / 256, 256, 0, stream>>>(qkv, cosT, sinT, Qr, Kr);
  k_vtrans<<<dim3(64, Bsz * KVsz), 256, 0, stream>>>(qkv, Vt);

  // 4. causal GQA attention -> AO [B,S,H*D] bf16
  k_attn<<<dim3(Ssz / 256, Bsz * Hsz), 512, 0, stream>>>(Qr, Kr, Vt, AO);

  // 5. o_proj: [4096,4096] x [4096,4096]^T -> d_out fp32
  k_gemm256<false><<<dim3((HIDsz / 256) * ((Bsz * Ssz) / 256)), 512, 0, stream>>>(
      AO, Wo_bf, (float*)d_out, Bsz * Ssz, HIDsz, HIDsz);
}

// Round 5
// 673.546 us; speedup vs baseline: 1.6231x; 1.0451x over previous
//
#include <hip/hip_runtime.h>
#include <stdint.h>
#include <stddef.h>

#define Bsz   2
#define Ssz   2048
#define HIDsz 4096
#define Hsz   32
#define KVsz  8
#define Dsz   128
#define NQKV  6144                     // (H+2KV)*D
#define RSCALE 0.08838834764831845f    // 1/sqrt(128)

typedef __bf16 bf16x8 __attribute__((ext_vector_type(8)));
typedef float  f32x4  __attribute__((ext_vector_type(4)));
typedef float  f32x16 __attribute__((ext_vector_type(16)));
typedef unsigned short u16;
typedef u16 u16x4 __attribute__((ext_vector_type(4)));
typedef u16 u16x8 __attribute__((ext_vector_type(8)));
typedef uint32_t u32x4 __attribute__((ext_vector_type(4)));

__device__ __forceinline__ u16 f2bf(float f) {
  uint32_t u = __builtin_bit_cast(uint32_t, f);
  u = (u + 0x7FFFu + ((u >> 16) & 1u)) >> 16;   // RNE
  return (u16)u;
}
__device__ __forceinline__ u16 f2bf_fast(float f) {  // round-half-up, 2 VALU
  uint32_t u = __builtin_bit_cast(uint32_t, f);
  return (u16)((u + 0x8000u) >> 16);
}
__device__ __forceinline__ float bf2f(u16 h) {
  return __builtin_bit_cast(float, (uint32_t)h << 16);
}
__device__ __forceinline__ uint32_t packbf2(float lo, float hi_) {
  return (uint32_t)f2bf_fast(lo) | ((uint32_t)f2bf_fast(hi_) << 16);
}

// global -> LDS async copy, 16B per lane; LDS dest = wave-uniform base + lane*16
#define GLDS(gp, lp) __builtin_amdgcn_global_load_lds( \
    (__attribute__((address_space(1))) void*)(void*)(gp), \
    (__attribute__((address_space(3))) void*)(lp), 16, 0, 0)

// ---------------- elementwise conversions ----------------
__global__ __launch_bounds__(256) void k_cvt_bf16(const float* __restrict__ in,
                                                  u16* __restrict__ out, int n4) {
  int i = blockIdx.x * 256 + threadIdx.x;
  if (i >= n4) return;
  float4 v = ((const float4*)in)[i];
  u16x4 o;
  o.x = f2bf(v.x); o.y = f2bf(v.y); o.z = f2bf(v.z); o.w = f2bf(v.w);
  ((u16x4*)out)[i] = o;
}

// cos/sin table [B*S][64]
__global__ __launch_bounds__(256) void k_cs(const int* __restrict__ pos,
                                            float* __restrict__ cosT,
                                            float* __restrict__ sinT) {
  int idx = blockIdx.x * 256 + threadIdx.x;       // B*S*64
  if (idx >= Bsz * Ssz * 64) return;
  int j = idx & 63;
  int bs = idx >> 6;
  float p = (float)pos[bs];
  float inv = __expf(-(float)j * (9.210340371976184f / 64.0f));
  float ang = p * inv;
  cosT[idx] = __cosf(ang);
  sinT[idx] = __sinf(ang);
}

// RoPE on q,k; q scaled by 1/sqrt(D); writes Qr[b][h][s][d], Kr[b][kvh][s][d]
__global__ __launch_bounds__(256) void k_rope(const u16* __restrict__ qkv,
                                              const float* __restrict__ cosT,
                                              const float* __restrict__ sinT,
                                              u16* __restrict__ Qr, u16* __restrict__ Kr) {
  int idx = blockIdx.x * 256 + threadIdx.x;       // B*S*(H+KV)*64
  if (idx >= Bsz * Ssz * (Hsz + KVsz) * 64) return;
  int j = idx & 63;
  int head = (idx >> 6) % (Hsz + KVsz);
  int bs = idx / (64 * (Hsz + KVsz));
  const u16* row = qkv + (size_t)bs * NQKV + head * Dsz;
  float x1 = bf2f(row[j]), x2 = bf2f(row[j + 64]);
  float c = cosT[bs * 64 + j], s = sinT[bs * 64 + j];
  float o1 = x1 * c - x2 * s;
  float o2 = x2 * c + x1 * s;
  int b = bs / Ssz, sidx = bs % Ssz;
  if (head < Hsz) {
    u16* o = Qr + ((size_t)(b * Hsz + head) * Ssz + sidx) * Dsz;
    o[j] = f2bf(o1 * RSCALE); o[j + 64] = f2bf(o2 * RSCALE);
  } else {
    int kvh = head - Hsz;
    u16* o = Kr + ((size_t)(b * KVsz + kvh) * Ssz + sidx) * Dsz;
    o[j] = f2bf(o1); o[j + 64] = f2bf(o2);
  }
}

// V transpose, LDS-tiled: Vt[b][kvh][d][s] = qkv[b,s, (H+KV)*D + kvh*D + d]
__global__ __launch_bounds__(256) void k_vtrans(const u16* __restrict__ qkv,
                                                u16* __restrict__ Vt) {
  __shared__ __align__(16) u16 Tl[64 * 72];
  const int tid = threadIdx.x;
  const int bk = blockIdx.y;                      // b*KV + kvh
  const int s0 = (blockIdx.x >> 1) * 64;
  const int d0 = (blockIdx.x & 1) * 64;
  const int b = bk >> 3, kvh = bk & 7;
  const u16* src = qkv + (size_t)(b * Ssz + s0) * NQKV + (Hsz + KVsz) * Dsz + kvh * Dsz + d0;
#pragma unroll
  for (int p = 0; p < 2; ++p) {
    int cid = p * 256 + tid;
    int r = cid >> 3, co = cid & 7;
    int chunk = co ^ ((r >> 3) & 7);
    *(u16x8*)((char*)Tl + r * 144 + chunk * 16) =
        *(const u16x8*)(src + (size_t)r * NQKV + co * 8);
  }
  __syncthreads();
#pragma unroll
  for (int p = 0; p < 2; ++p) {
    int cid = p * 256 + tid;
    int dr = cid >> 3, c = cid & 7;
    u16x8 v;
#pragma unroll
    for (int j = 0; j < 8; ++j) {
      int s = 8 * c + j;
      v[j] = *(const u16*)((char*)Tl + s * 144 + (((dr >> 3) ^ c) * 16) + (dr & 7) * 2);
    }
    *(u16x8*)(Vt + ((size_t)bk * Dsz + d0 + dr) * Ssz + s0 + 8 * c) = v;
  }
}

// ============ 256x256 8-phase GEMM: C[M][N] = A[M][K] * B[N][K]^T ============
// v2: single barrier per phase, compiler-managed lgkm waits (no sched pinning),
// A-frags software-pipelined one phase ahead (ping-pong reg set), B-frags once
// per 4-phase group. Stage/tile schedule identical to the verified r3 ledger:
//   iter i (tiles 2i@buf0, 2i+1@buf1):
//   Q0: LDB+LDA(Q0) MMA0 pref(Q1) STAGE T1.A1->b1 | Q1: MMA1 pref(Q2) T2.B0->b0
//   Q2: MMA2 pref(Q3) T2.B1->b0 | Q3: MMA3 T2.A0->b0 vmcnt(6)
//   Q4: LDB+LDA MMA0 pref T2.A1->b0 | Q5: MMA1 pref T3.B0->b1
//   Q6: MMA2 pref T3.A0->b1 | Q7: MMA3 T3.B1->b1 vmcnt(6)
// Liveness: every staged half lands >=1 barrier after its last read's consuming
// MFMA (reads complete before their MFMA by data-dep; stage issued after the
// following barrier). vmcnt(6)@Q3 completes T1; @Q7 completes T2.

#define BARX do { asm volatile("" ::: "memory"); __builtin_amdgcn_s_barrier(); \
                  asm volatile("" ::: "memory"); } while (0)
#define VM6  asm volatile("s_waitcnt vmcnt(6)" ::: "memory")
#define VM0  asm volatile("s_waitcnt vmcnt(0)" ::: "memory")

#define LOADA4(P_, Q_, F_) do {                                               \
    afr[F_][0] = LDA(P_, Q_, 0, 0); afr[F_][1] = LDA(P_, Q_, 0, 1);           \
    afr[F_][2] = LDA(P_, Q_, 1, 0); afr[F_][3] = LDA(P_, Q_, 1, 1);           \
  } while (0)

#define LOADB8(P_) do {                                                       \
    _Pragma("unroll") for (int nf = 0; nf < 4; ++nf) {                        \
      bfr[nf][0] = LDB(P_, nf, 0); bfr[nf][1] = LDB(P_, nf, 1); }             \
  } while (0)

#define MMA16(Q_, F_) do {                                                    \
    __builtin_amdgcn_s_setprio(1);                                            \
    _Pragma("unroll") for (int nf = 0; nf < 4; ++nf) {                        \
      acc[(Q_)*2][nf]   = __builtin_amdgcn_mfma_f32_16x16x32_bf16(afr[F_][0], bfr[nf][0], acc[(Q_)*2][nf],   0,0,0); \
      acc[(Q_)*2][nf]   = __builtin_amdgcn_mfma_f32_16x16x32_bf16(afr[F_][1], bfr[nf][1], acc[(Q_)*2][nf],   0,0,0); \
      acc[(Q_)*2+1][nf] = __builtin_amdgcn_mfma_f32_16x16x32_bf16(afr[F_][2], bfr[nf][0], acc[(Q_)*2+1][nf], 0,0,0); \
      acc[(Q_)*2+1][nf] = __builtin_amdgcn_mfma_f32_16x16x32_bf16(afr[F_][3], bfr[nf][1], acc[(Q_)*2+1][nf], 0,0,0); \
    }                                                                         \
    __builtin_amdgcn_s_setprio(0);                                            \
  } while (0)

template <bool BF16OUT>
__global__ __launch_bounds__(512, 2) void k_gemm256(const u16* __restrict__ A,
                                                    const u16* __restrict__ Bm,
                                                    void* __restrict__ Cv,
                                                    int M, int N, int K) {
  __shared__ __align__(16) u16 SA[2][256 * 64];
  __shared__ __align__(16) u16 SB[2][256 * 64];
  const int tid = threadIdx.x;
  const int w = tid >> 6, lane = tid & 63;
  const int g = lane >> 4, t = lane & 15;
  const int wr = w >> 2, wc = w & 3;
  const int NB = N >> 8;
  const int cpx = gridDim.x >> 3;                 // grid %8 == 0 (384 / 256)
  const int swz = (blockIdx.x & 7) * cpx + (blockIdx.x >> 3);
  const int bm = swz / NB, bn = swz % NB;
  const int m0 = bm << 8, n0 = bn << 8;

  const char* Ab = (const char*)A;
  const char* Bb = (const char*)Bm;
  const size_t rowK = (size_t)K * 2;              // bytes per input row
  const int srcx = ((lane & 7) ^ (lane >> 3)) << 4;  // pre-swizzled src col
  const int l3 = lane >> 3;
  const int tx = (t & 7) << 4;                    // read-side XOR (bytes)

  auto SToff = [&](int h, int j) -> int {
    int ii = w * 2 + j;
    return (ii < 8) ? (h * 64 + ii * 8) : (128 + h * 64 + (ii - 8) * 8);
  };
  auto STAGE_A = [&](int p, int T, int h) {
#pragma unroll
    for (int j = 0; j < 2; ++j) {
      int rb = SToff(h, j);
      GLDS(Ab + (size_t)(m0 + rb + l3) * rowK + (size_t)T * 128 + srcx,
           &SA[p][rb * 64]);
    }
  };
  auto STAGE_B = [&](int p, int T, int h) {
#pragma unroll
    for (int j = 0; j < 2; ++j) {
      int rb = SToff(h, j);
      GLDS(Bb + (size_t)(n0 + rb + l3) * rowK + (size_t)T * 128 + srcx,
           &SB[p][rb * 64]);
    }
  };
  auto LDA = [&](int p, int q, int fr, int kk) -> bf16x8 {
    int ar = wr * 128 + q * 32 + fr * 16 + t;
    const char* ptr = (const char*)&SA[p][0] + ar * 128 + ((kk * 64 + 16 * g) ^ tx);
    return __builtin_bit_cast(bf16x8, *(const u16x8*)ptr);
  };
  auto LDB = [&](int p, int nf, int kk) -> bf16x8 {
    int br = wc * 64 + nf * 16 + t;
    const char* ptr = (const char*)&SB[p][0] + br * 128 + ((kk * 64 + 16 * g) ^ tx);
    return __builtin_bit_cast(bf16x8, *(const u16x8*)ptr);
  };

  f32x4 acc[8][4];
#pragma unroll
  for (int i = 0; i < 8; ++i)
#pragma unroll
    for (int j = 0; j < 4; ++j) acc[i][j] = (f32x4){0.f, 0.f, 0.f, 0.f};
  bf16x8 bfr[4][2];
  bf16x8 afr[2][4];

  // prologue: T0 complete (8 loads) + T1.{A0,B0,B1} (6 loads)
  STAGE_A(0, 0, 0); STAGE_B(0, 0, 0); STAGE_A(0, 0, 1); STAGE_B(0, 0, 1);
  STAGE_A(1, 1, 0); STAGE_B(1, 1, 0); STAGE_B(1, 1, 1);
  VM6;                                            // T0 landed
  __builtin_amdgcn_s_barrier();

  const int NI = (K >> 7) - 1;
  for (int i = 0; i < NI; ++i) {
    const int T1 = 2 * i + 1, T2 = 2 * i + 2, T3 = 2 * i + 3;
    LOADB8(0); LOADA4(0, 0, 0);
    MMA16(0, 0); LOADA4(0, 1, 1); STAGE_A(1, T1, 1); BARX;
    MMA16(1, 1); LOADA4(0, 2, 0); STAGE_B(0, T2, 0); BARX;
    MMA16(2, 0); LOADA4(0, 3, 1); STAGE_B(0, T2, 1); BARX;
    MMA16(3, 1); STAGE_A(0, T2, 0); VM6; BARX;
    LOADB8(1); LOADA4(1, 0, 0);
    MMA16(0, 0); LOADA4(1, 1, 1); STAGE_A(0, T2, 1); BARX;
    MMA16(1, 1); LOADA4(1, 2, 0); STAGE_B(1, T3, 0); BARX;
    MMA16(2, 0); LOADA4(1, 3, 1); STAGE_A(1, T3, 0); BARX;
    MMA16(3, 1); STAGE_B(1, T3, 1); VM6; BARX;
  }
  {                                               // peeled final iteration
    const int TL = (K >> 6) - 1;
    LOADB8(0); LOADA4(0, 0, 0);
    MMA16(0, 0); LOADA4(0, 1, 1); STAGE_A(1, TL, 1); BARX;
    MMA16(1, 1); LOADA4(0, 2, 0); BARX;
    MMA16(2, 0); LOADA4(0, 3, 1); BARX;
    MMA16(3, 1); VM0; BARX;
    LOADB8(1); LOADA4(1, 0, 0);
    MMA16(0, 0); LOADA4(1, 1, 1); BARX;
    MMA16(1, 1); LOADA4(1, 2, 0); BARX;
    MMA16(2, 0); LOADA4(1, 3, 1); BARX;
    MMA16(3, 1);
  }

  // epilogue: C-write (row = 4*(lane>>4)+reg, col = lane&15)
#pragma unroll
  for (int fi = 0; fi < 8; ++fi)
#pragma unroll
    for (int nf = 0; nf < 4; ++nf)
#pragma unroll
      for (int r = 0; r < 4; ++r) {
        int row = m0 + wr * 128 + fi * 16 + 4 * g + r;
        int col = n0 + wc * 64 + nf * 16 + t;
        float v = acc[fi][nf][r];
        if constexpr (BF16OUT) ((u16*)Cv)[(size_t)row * N + col] = f2bf(v);
        else                   ((float*)Cv)[(size_t)row * N + col] = v;
      }
}

// ---------------- flash attention: 8-wave swapped-QK^T 32x32 ----------------
__global__ __launch_bounds__(512, 2) void k_attn(const u16* __restrict__ Qr,
                                                 const u16* __restrict__ Kr,
                                                 const u16* __restrict__ Vt,
                                                 u16* __restrict__ AO) {
  __shared__ __align__(16) u16 Kl[2][64 * 128];  // [k][d] swizzled
  __shared__ __align__(16) u16 Vl[2][128 * 64];  // [d][k] swizzled
  const int tid = threadIdx.x;
  const int w = tid >> 6, lane = tid & 63;
  const int q = lane & 31, hi = lane >> 5;
  const int bh = blockIdx.y;
  const int b = bh >> 5, h = bh & 31;
  const int kvh = h >> 2;                        // GQA: H/KV = 4
  const int bxr = gridDim.x - 1 - blockIdx.x;    // longest blocks first
  const int q0 = bxr * 256;
  const int qw = q0 + w * 32;
  const int ntiles = 4 * bxr + 4;
  const int qg = qw + q;

  const u16* Qb = Qr + ((size_t)bh * Ssz + qw + q) * Dsz + hi * 8;
  bf16x8 qf[8];
#pragma unroll
  for (int ds = 0; ds < 8; ++ds)
    qf[ds] = __builtin_bit_cast(bf16x8, *(const u16x8*)(Qb + ds * 16));

  f32x16 oacc[4];
#pragma unroll
  for (int dt = 0; dt < 4; ++dt)
#pragma unroll
    for (int r = 0; r < 16; ++r) oacc[dt][r] = 0.f;
  float mr = -1e30f, lr = 0.f;

  const char* Kbase = (const char*)(Kr + (size_t)(b * KVsz + kvh) * Ssz * Dsz);
  const char* Vbase = (const char*)(Vt + (size_t)(b * KVsz + kvh) * Dsz * Ssz);

  auto STAGE = [&](int bu, int kt2) {
    const char* Kb = Kbase + (size_t)kt2 * (64 * 256);
    const char* Vb = Vbase + (size_t)kt2 * 128;   // 64 cols * 2B
#pragma unroll
    for (int j = 0; j < 2; ++j) {
      int flat = j * 512 + tid;
      int row = flat >> 4, colb = ((flat & 15) * 16) ^ ((row & 7) << 4);
      GLDS(Kb + (size_t)row * 256 + colb, (char*)&Kl[bu][0] + flat * 16);
    }
#pragma unroll
    for (int j = 0; j < 2; ++j) {
      int flat = j * 512 + tid;
      int row = flat >> 3, colb = ((flat & 7) * 16) ^ ((row & 7) << 4);
      GLDS(Vb + (size_t)row * (Ssz * 2) + colb, (char*)&Vl[bu][0] + flat * 16);
    }
  };

  int buf = 0;
  STAGE(0, 0);
  __syncthreads();

  for (int kt = 0; kt < ntiles; ++kt) {
    const int k0 = kt * 64;
    if (kt + 1 < ntiles) STAGE(buf ^ 1, kt + 1);   // prefetch overlaps compute

    if (k0 <= qw + 31) {                           // wave participates
      f32x16 pa0, pa1;
#pragma unroll
      for (int r = 0; r < 16; ++r) { pa0[r] = 0.f; pa1[r] = 0.f; }
      __builtin_amdgcn_s_setprio(1);
#pragma unroll
      for (int ds = 0; ds < 8; ++ds) {
        {
          const int row = q;
          const char* kp = (const char*)&Kl[buf][0] + row * 256 +
                           ((ds * 32 + hi * 16) ^ ((row & 7) << 4));
          bf16x8 kf = __builtin_bit_cast(bf16x8, *(const u16x8*)kp);
          pa0 = __builtin_amdgcn_mfma_f32_32x32x16_bf16(kf, qf[ds], pa0, 0, 0, 0);
        }
        {
          const int row = 32 + q;
          const char* kp = (const char*)&Kl[buf][0] + row * 256 +
                           ((ds * 32 + hi * 16) ^ ((row & 7) << 4));
          bf16x8 kf = __builtin_bit_cast(bf16x8, *(const u16x8*)kp);
          pa1 = __builtin_amdgcn_mfma_f32_32x32x16_bf16(kf, qf[ds], pa1, 0, 0, 0);
        }
      }
      __builtin_amdgcn_s_setprio(0);

      if (k0 + 63 > qw) {
#pragma unroll
        for (int reg = 0; reg < 16; ++reg) {
          const int kb = (reg & 3) + 8 * (reg >> 2) + 4 * hi;
          if (k0 + kb > qg)      pa0[reg] = -1e30f;
          if (k0 + 32 + kb > qg) pa1[reg] = -1e30f;
        }
      }
      float mx = -1e30f;
#pragma unroll
      for (int reg = 0; reg < 16; ++reg) mx = fmaxf(mx, fmaxf(pa0[reg], pa1[reg]));
      mx = fmaxf(mx, __shfl_xor(mx, 32, 64));
      const float mnew = fmaxf(mr, mx);
      const float corr = __expf(mr - mnew);
      float ps = 0.f;
#pragma unroll
      for (int reg = 0; reg < 16; ++reg) {
        pa0[reg] = __expf(pa0[reg] - mnew);
        pa1[reg] = __expf(pa1[reg] - mnew);
        ps += pa0[reg] + pa1[reg];
      }
      ps += __shfl_xor(ps, 32, 64);
      lr = lr * corr + ps;
      mr = mnew;
#pragma unroll
      for (int dt = 0; dt < 4; ++dt)
#pragma unroll
        for (int reg = 0; reg < 16; ++reg) oacc[dt][reg] *= corr;

      uint32_t W[2][4][2], X[2][4][2];
#pragma unroll
      for (int r2 = 0; r2 < 4; ++r2)
#pragma unroll
        for (int c = 0; c < 2; ++c) {
          W[0][r2][c] = packbf2(pa0[4 * r2 + 2 * c], pa0[4 * r2 + 2 * c + 1]);
          W[1][r2][c] = packbf2(pa1[4 * r2 + 2 * c], pa1[4 * r2 + 2 * c + 1]);
        }
#pragma unroll
      for (int T = 0; T < 2; ++T)
#pragma unroll
        for (int r2 = 0; r2 < 4; ++r2)
#pragma unroll
          for (int c = 0; c < 2; ++c)
            X[T][r2][c] = __shfl_xor(W[T][r2][c], 32, 64);

      __builtin_amdgcn_s_setprio(1);
#pragma unroll
      for (int ks = 0; ks < 4; ++ks) {
        const int T = ks >> 1, r2e = 2 * (ks & 1);
        u32x4 fw;
        fw[0] = hi ? X[T][r2e + 1][0] : W[T][r2e][0];
        fw[1] = hi ? X[T][r2e + 1][1] : W[T][r2e][1];
        fw[2] = hi ? W[T][r2e + 1][0] : X[T][r2e][0];
        fw[3] = hi ? W[T][r2e + 1][1] : X[T][r2e][1];
        bf16x8 pf = __builtin_bit_cast(bf16x8, fw);
#pragma unroll
        for (int dt = 0; dt < 4; ++dt) {
          const int row = dt * 32 + q;
          const char* vp = (const char*)&Vl[buf][0] + row * 128 +
                           ((ks * 32 + hi * 16) ^ ((row & 7) << 4));
          bf16x8 vf = __builtin_bit_cast(bf16x8, *(const u16x8*)vp);
          oacc[dt] = __builtin_amdgcn_mfma_f32_32x32x16_bf16(vf, pf, oacc[dt], 0, 0, 0);
        }
      }
      __builtin_amdgcn_s_setprio(0);
    }
    __syncthreads();                             // drains vmcnt: next buffer ready
    buf ^= 1;
  }

  const float inv = 1.f / lr;
  u16* Ob = AO + ((size_t)(b * Ssz) + qw + q) * HIDsz + h * Dsz + hi * 4;
#pragma unroll
  for (int dt = 0; dt < 4; ++dt)
#pragma unroll
    for (int r2 = 0; r2 < 4; ++r2) {
      u16x4 o4;
#pragma unroll
      for (int j = 0; j < 4; ++j) o4[j] = f2bf(oacc[dt][4 * r2 + j] * inv);
      *(u16x4*)(Ob + dt * 32 + r2 * 8) = o4;
    }
}

// ---------------- host ----------------
extern "C" void kernel_launch(void* const* d_in, const int* in_sizes, int n_in,
                              void* d_out, int out_size, void* d_ws, size_t ws_size,
                              hipStream_t stream) {
  (void)in_sizes; (void)n_in; (void)out_size;
  const float* hs   = (const float*)d_in[0];
  const int*   pos  = (const int*)d_in[1];
  const float* Wqkv = (const float*)d_in[2];
  const float* Wo   = (const float*)d_in[3];

  char* ws = (char*)d_ws;
  const size_t SZ_XBF = (size_t)4096 * 4096 * 2;   // also reused for AO
  const size_t SZ_WQ  = (size_t)6144 * 4096 * 2;
  const size_t SZ_WO  = (size_t)4096 * 4096 * 2;
  const size_t SZ_QKV = (size_t)4096 * 6144 * 2;
  const size_t SZ_QR  = (size_t)Bsz * Hsz * Ssz * Dsz * 2;
  const size_t SZ_KR  = (size_t)Bsz * KVsz * Ssz * Dsz * 2;
  const size_t SZ_VT  = SZ_KR;
  const size_t SZ_CS  = (size_t)Bsz * Ssz * 64 * 4;

  size_t off = 0;
  u16*   Xbf   = (u16*)(ws + off);  off += SZ_XBF;
  u16*   Wq_bf = (u16*)(ws + off);  off += SZ_WQ;
  u16*   Wo_bf = (u16*)(ws + off);  off += SZ_WO;
  u16*   qkv   = (u16*)(ws + off);  off += SZ_QKV;
  u16*   Qr    = (u16*)(ws + off);  off += SZ_QR;
  u16*   Kr    = (u16*)(ws + off);  off += SZ_KR;
  u16*   Vt    = (u16*)(ws + off);  off += SZ_VT;
  float* cosT  = (float*)(ws + off); off += SZ_CS;
  float* sinT  = (float*)(ws + off); off += SZ_CS;
  u16*   AO    = Xbf;                               // alias (Xbf dead after gemm1)
  if (ws_size < off) return;                        // fail loudly

  // 1. fp32 -> bf16 conversions
  k_cvt_bf16<<<(Bsz * Ssz * HIDsz) / 1024, 256, 0, stream>>>(hs, Xbf, (Bsz * Ssz * HIDsz) / 4);
  k_cvt_bf16<<<(NQKV * HIDsz) / 1024, 256, 0, stream>>>(Wqkv, Wq_bf, (NQKV * HIDsz) / 4);
  k_cvt_bf16<<<(HIDsz * HIDsz) / 1024, 256, 0, stream>>>(Wo, Wo_bf, (HIDsz * HIDsz) / 4);

  // 2. QKV projection: [4096,4096] x [6144,4096]^T -> [4096,6144]
  k_gemm256<true><<<dim3((NQKV / 256) * ((Bsz * Ssz) / 256)), 512, 0, stream>>>(
      Xbf, Wq_bf, qkv, Bsz * Ssz, NQKV, HIDsz);

  // 3. RoPE tables + apply + V transpose
  k_cs<<<(Bsz * Ssz * 64) / 256, 256, 0, stream>>>(pos, cosT, sinT);
  k_rope<<<(Bsz * Ssz * (Hsz + KVsz) * 64) / 256, 256, 0, stream>>>(qkv, cosT, sinT, Qr, Kr);
  k_vtrans<<<dim3(64, Bsz * KVsz), 256, 0, stream>>>(qkv, Vt);

  // 4. causal GQA attention -> AO [B,S,H*D] bf16
  k_attn<<<dim3(Ssz / 256, Bsz * Hsz), 512, 0, stream>>>(Qr, Kr, Vt, AO);

  // 5. o_proj: [4096,4096] x [4096,4096]^T -> d_out fp32
  k_gemm256<false><<<dim3((HIDsz / 256) * ((Bsz * Ssz) / 256)), 512, 0, stream>>>(
      AO, Wo_bf, (float*)d_out, Bsz * Ssz, HIDsz, HIDsz);
}

// Round 6
// 645.289 us; speedup vs baseline: 1.6942x; 1.0438x over previous
//
#include <hip/hip_runtime.h>
#include <stdint.h>
#include <stddef.h>

#define Bsz   2
#define Ssz   2048
#define HIDsz 4096
#define Hsz   32
#define KVsz  8
#define Dsz   128
#define NQKV  6144                     // (H+2KV)*D
#define RSCALE 0.08838834764831845f    // 1/sqrt(128)

typedef __bf16 bf16x8 __attribute__((ext_vector_type(8)));
typedef float  f32x4  __attribute__((ext_vector_type(4)));
typedef float  f32x16 __attribute__((ext_vector_type(16)));
typedef unsigned short u16;
typedef u16 u16x4 __attribute__((ext_vector_type(4)));
typedef u16 u16x8 __attribute__((ext_vector_type(8)));
typedef uint32_t u32x4 __attribute__((ext_vector_type(4)));

__device__ __forceinline__ u16 f2bf(float f) {
  uint32_t u = __builtin_bit_cast(uint32_t, f);
  u = (u + 0x7FFFu + ((u >> 16) & 1u)) >> 16;   // RNE
  return (u16)u;
}
__device__ __forceinline__ u16 f2bf_fast(float f) {  // round-half-up, 2 VALU
  uint32_t u = __builtin_bit_cast(uint32_t, f);
  return (u16)((u + 0x8000u) >> 16);
}
__device__ __forceinline__ float bf2f(u16 h) {
  return __builtin_bit_cast(float, (uint32_t)h << 16);
}
__device__ __forceinline__ uint32_t packbf2(float lo, float hi_) {
  return (uint32_t)f2bf_fast(lo) | ((uint32_t)f2bf_fast(hi_) << 16);
}

// global -> LDS async copy, 16B per lane; LDS dest = wave-uniform base + lane*16
#define GLDS(gp, lp) __builtin_amdgcn_global_load_lds( \
    (__attribute__((address_space(1))) void*)(void*)(gp), \
    (__attribute__((address_space(3))) void*)(lp), 16, 0, 0)

// ---------------- elementwise conversions ----------------
__global__ __launch_bounds__(256) void k_cvt_bf16(const float* __restrict__ in,
                                                  u16* __restrict__ out, int n4) {
  int i = blockIdx.x * 256 + threadIdx.x;
  if (i >= n4) return;
  float4 v = ((const float4*)in)[i];
  u16x4 o;
  o.x = f2bf(v.x); o.y = f2bf(v.y); o.z = f2bf(v.z); o.w = f2bf(v.w);
  ((u16x4*)out)[i] = o;
}

// cos/sin table [B*S][64]
__global__ __launch_bounds__(256) void k_cs(const int* __restrict__ pos,
                                            float* __restrict__ cosT,
                                            float* __restrict__ sinT) {
  int idx = blockIdx.x * 256 + threadIdx.x;       // B*S*64
  if (idx >= Bsz * Ssz * 64) return;
  int j = idx & 63;
  int bs = idx >> 6;
  float p = (float)pos[bs];
  float inv = __expf(-(float)j * (9.210340371976184f / 64.0f));
  float ang = p * inv;
  cosT[idx] = __cosf(ang);
  sinT[idx] = __sinf(ang);
}

// RoPE on q,k; q scaled by 1/sqrt(D); writes Qr[b][h][s][d], Kr[b][kvh][s][d]
__global__ __launch_bounds__(256) void k_rope(const u16* __restrict__ qkv,
                                              const float* __restrict__ cosT,
                                              const float* __restrict__ sinT,
                                              u16* __restrict__ Qr, u16* __restrict__ Kr) {
  int idx = blockIdx.x * 256 + threadIdx.x;       // B*S*(H+KV)*64
  if (idx >= Bsz * Ssz * (Hsz + KVsz) * 64) return;
  int j = idx & 63;
  int head = (idx >> 6) % (Hsz + KVsz);
  int bs = idx / (64 * (Hsz + KVsz));
  const u16* row = qkv + (size_t)bs * NQKV + head * Dsz;
  float x1 = bf2f(row[j]), x2 = bf2f(row[j + 64]);
  float c = cosT[bs * 64 + j], s = sinT[bs * 64 + j];
  float o1 = x1 * c - x2 * s;
  float o2 = x2 * c + x1 * s;
  int b = bs / Ssz, sidx = bs % Ssz;
  if (head < Hsz) {
    u16* o = Qr + ((size_t)(b * Hsz + head) * Ssz + sidx) * Dsz;
    o[j] = f2bf(o1 * RSCALE); o[j + 64] = f2bf(o2 * RSCALE);
  } else {
    int kvh = head - Hsz;
    u16* o = Kr + ((size_t)(b * KVsz + kvh) * Ssz + sidx) * Dsz;
    o[j] = f2bf(o1); o[j + 64] = f2bf(o2);
  }
}

// V transpose, LDS-tiled: Vt[b][kvh][d][s] = qkv[b,s, (H+KV)*D + kvh*D + d]
__global__ __launch_bounds__(256) void k_vtrans(const u16* __restrict__ qkv,
                                                u16* __restrict__ Vt) {
  __shared__ __align__(16) u16 Tl[64 * 72];
  const int tid = threadIdx.x;
  const int bk = blockIdx.y;                      // b*KV + kvh
  const int s0 = (blockIdx.x >> 1) * 64;
  const int d0 = (blockIdx.x & 1) * 64;
  const int b = bk >> 3, kvh = bk & 7;
  const u16* src = qkv + (size_t)(b * Ssz + s0) * NQKV + (Hsz + KVsz) * Dsz + kvh * Dsz + d0;
#pragma unroll
  for (int p = 0; p < 2; ++p) {
    int cid = p * 256 + tid;
    int r = cid >> 3, co = cid & 7;
    int chunk = co ^ ((r >> 3) & 7);
    *(u16x8*)((char*)Tl + r * 144 + chunk * 16) =
        *(const u16x8*)(src + (size_t)r * NQKV + co * 8);
  }
  __syncthreads();
#pragma unroll
  for (int p = 0; p < 2; ++p) {
    int cid = p * 256 + tid;
    int dr = cid >> 3, c = cid & 7;
    u16x8 v;
#pragma unroll
    for (int j = 0; j < 8; ++j) {
      int s = 8 * c + j;
      v[j] = *(const u16*)((char*)Tl + s * 144 + (((dr >> 3) ^ c) * 16) + (dr & 7) * 2);
    }
    *(u16x8*)(Vt + ((size_t)bk * Dsz + d0 + dr) * Ssz + s0 + 8 * c) = v;
  }
}

// ============ 256x256 8-phase GEMM: C[M][N] = A[M][K] * B[N][K]^T ============
// v3: per-acc MFMA pairs (kk0->kk1) were emitted back-to-back (dependent
// distance 1); reordered into two passes over the 8 independent acc-frags so
// dependent distance = 8 (same per-acc accumulation order -> bit-identical).
// STAGE + next-phase ds_reads now issue BEFORE the MFMA cluster (T3 recipe).
// Stage/tile ledger identical to r3/r5 (verified): vmcnt(6)@Q3 completes T1,
// @Q7 completes T2; every staged half lands >=1 barrier after its last read.

#define BARX do { asm volatile("" ::: "memory"); __builtin_amdgcn_s_barrier(); \
                  asm volatile("" ::: "memory"); } while (0)
#define VM6  asm volatile("s_waitcnt vmcnt(6)" ::: "memory")
#define VM0  asm volatile("s_waitcnt vmcnt(0)" ::: "memory")

#define LOADA4(P_, Q_, F_) do {                                               \
    afr[F_][0] = LDA(P_, Q_, 0, 0); afr[F_][1] = LDA(P_, Q_, 0, 1);           \
    afr[F_][2] = LDA(P_, Q_, 1, 0); afr[F_][3] = LDA(P_, Q_, 1, 1);           \
  } while (0)

#define LOADB8(P_) do {                                                       \
    _Pragma("unroll") for (int nf = 0; nf < 4; ++nf) {                        \
      bfr[nf][0] = LDB(P_, nf, 0); bfr[nf][1] = LDB(P_, nf, 1); }             \
  } while (0)

// 16 MFMA, two passes over 8 independent acc-frags: dep distance = 8
#define MMA16(Q_, F_) do {                                                    \
    __builtin_amdgcn_s_setprio(1);                                            \
    _Pragma("unroll") for (int nf = 0; nf < 4; ++nf) {                        \
      acc[(Q_)*2][nf]   = __builtin_amdgcn_mfma_f32_16x16x32_bf16(afr[F_][0], bfr[nf][0], acc[(Q_)*2][nf],   0,0,0); \
      acc[(Q_)*2+1][nf] = __builtin_amdgcn_mfma_f32_16x16x32_bf16(afr[F_][2], bfr[nf][0], acc[(Q_)*2+1][nf], 0,0,0); \
    }                                                                         \
    _Pragma("unroll") for (int nf = 0; nf < 4; ++nf) {                        \
      acc[(Q_)*2][nf]   = __builtin_amdgcn_mfma_f32_16x16x32_bf16(afr[F_][1], bfr[nf][1], acc[(Q_)*2][nf],   0,0,0); \
      acc[(Q_)*2+1][nf] = __builtin_amdgcn_mfma_f32_16x16x32_bf16(afr[F_][3], bfr[nf][1], acc[(Q_)*2+1][nf], 0,0,0); \
    }                                                                         \
    __builtin_amdgcn_s_setprio(0);                                            \
  } while (0)

template <bool BF16OUT>
__global__ __launch_bounds__(512, 2) void k_gemm256(const u16* __restrict__ A,
                                                    const u16* __restrict__ Bm,
                                                    void* __restrict__ Cv,
                                                    int M, int N, int K) {
  __shared__ __align__(16) u16 SA[2][256 * 64];
  __shared__ __align__(16) u16 SB[2][256 * 64];
  const int tid = threadIdx.x;
  const int w = tid >> 6, lane = tid & 63;
  const int g = lane >> 4, t = lane & 15;
  const int wr = w >> 2, wc = w & 3;
  const int NB = N >> 8;
  const int cpx = gridDim.x >> 3;                 // grid %8 == 0 (384 / 256)
  const int swz = (blockIdx.x & 7) * cpx + (blockIdx.x >> 3);
  const int bm = swz / NB, bn = swz % NB;
  const int m0 = bm << 8, n0 = bn << 8;

  const char* Ab = (const char*)A;
  const char* Bb = (const char*)Bm;
  const size_t rowK = (size_t)K * 2;              // bytes per input row
  const int srcx = ((lane & 7) ^ (lane >> 3)) << 4;  // pre-swizzled src col
  const int l3 = lane >> 3;
  const int tx = (t & 7) << 4;                    // read-side XOR (bytes)

  auto SToff = [&](int h, int j) -> int {
    int ii = w * 2 + j;
    return (ii < 8) ? (h * 64 + ii * 8) : (128 + h * 64 + (ii - 8) * 8);
  };
  auto STAGE_A = [&](int p, int T, int h) {
#pragma unroll
    for (int j = 0; j < 2; ++j) {
      int rb = SToff(h, j);
      GLDS(Ab + (size_t)(m0 + rb + l3) * rowK + (size_t)T * 128 + srcx,
           &SA[p][rb * 64]);
    }
  };
  auto STAGE_B = [&](int p, int T, int h) {
#pragma unroll
    for (int j = 0; j < 2; ++j) {
      int rb = SToff(h, j);
      GLDS(Bb + (size_t)(n0 + rb + l3) * rowK + (size_t)T * 128 + srcx,
           &SB[p][rb * 64]);
    }
  };
  auto LDA = [&](int p, int q, int fr, int kk) -> bf16x8 {
    int ar = wr * 128 + q * 32 + fr * 16 + t;
    const char* ptr = (const char*)&SA[p][0] + ar * 128 + ((kk * 64 + 16 * g) ^ tx);
    return __builtin_bit_cast(bf16x8, *(const u16x8*)ptr);
  };
  auto LDB = [&](int p, int nf, int kk) -> bf16x8 {
    int br = wc * 64 + nf * 16 + t;
    const char* ptr = (const char*)&SB[p][0] + br * 128 + ((kk * 64 + 16 * g) ^ tx);
    return __builtin_bit_cast(bf16x8, *(const u16x8*)ptr);
  };

  f32x4 acc[8][4];
#pragma unroll
  for (int i = 0; i < 8; ++i)
#pragma unroll
    for (int j = 0; j < 4; ++j) acc[i][j] = (f32x4){0.f, 0.f, 0.f, 0.f};
  bf16x8 bfr[4][2];
  bf16x8 afr[2][4];

  // prologue: T0 complete (8 loads) + T1.{A0,B0,B1} (6 loads)
  STAGE_A(0, 0, 0); STAGE_B(0, 0, 0); STAGE_A(0, 0, 1); STAGE_B(0, 0, 1);
  STAGE_A(1, 1, 0); STAGE_B(1, 1, 0); STAGE_B(1, 1, 1);
  VM6;                                            // T0 landed
  __builtin_amdgcn_s_barrier();

  const int NI = (K >> 7) - 1;
  for (int i = 0; i < NI; ++i) {
    const int T1 = 2 * i + 1, T2 = 2 * i + 2, T3 = 2 * i + 3;
    LOADB8(0); LOADA4(0, 0, 0);
    STAGE_A(1, T1, 1); LOADA4(0, 1, 1); MMA16(0, 0); BARX;
    STAGE_B(0, T2, 0); LOADA4(0, 2, 0); MMA16(1, 1); BARX;
    STAGE_B(0, T2, 1); LOADA4(0, 3, 1); MMA16(2, 0); BARX;
    STAGE_A(0, T2, 0); MMA16(3, 1); VM6; BARX;
    LOADB8(1); LOADA4(1, 0, 0);
    STAGE_A(0, T2, 1); LOADA4(1, 1, 1); MMA16(0, 0); BARX;
    STAGE_B(1, T3, 0); LOADA4(1, 2, 0); MMA16(1, 1); BARX;
    STAGE_A(1, T3, 0); LOADA4(1, 3, 1); MMA16(2, 0); BARX;
    STAGE_B(1, T3, 1); MMA16(3, 1); VM6; BARX;
  }
  {                                               // peeled final iteration
    const int TL = (K >> 6) - 1;
    LOADB8(0); LOADA4(0, 0, 0);
    STAGE_A(1, TL, 1); LOADA4(0, 1, 1); MMA16(0, 0); BARX;
    LOADA4(0, 2, 0); MMA16(1, 1); BARX;
    LOADA4(0, 3, 1); MMA16(2, 0); BARX;
    MMA16(3, 1); VM0; BARX;
    LOADB8(1); LOADA4(1, 0, 0);
    LOADA4(1, 1, 1); MMA16(0, 0); BARX;
    LOADA4(1, 2, 0); MMA16(1, 1); BARX;
    LOADA4(1, 3, 1); MMA16(2, 0); BARX;
    MMA16(3, 1);
  }

  // epilogue: C-write (row = 4*(lane>>4)+reg, col = lane&15)
#pragma unroll
  for (int fi = 0; fi < 8; ++fi)
#pragma unroll
    for (int nf = 0; nf < 4; ++nf)
#pragma unroll
      for (int r = 0; r < 4; ++r) {
        int row = m0 + wr * 128 + fi * 16 + 4 * g + r;
        int col = n0 + wc * 64 + nf * 16 + t;
        float v = acc[fi][nf][r];
        if constexpr (BF16OUT) ((u16*)Cv)[(size_t)row * N + col] = f2bf(v);
        else                   ((float*)Cv)[(size_t)row * N + col] = v;
      }
}

// ---------------- flash attention: 8-wave swapped-QK^T 32x32 ----------------
__global__ __launch_bounds__(512, 2) void k_attn(const u16* __restrict__ Qr,
                                                 const u16* __restrict__ Kr,
                                                 const u16* __restrict__ Vt,
                                                 u16* __restrict__ AO) {
  __shared__ __align__(16) u16 Kl[2][64 * 128];  // [k][d] swizzled
  __shared__ __align__(16) u16 Vl[2][128 * 64];  // [d][k] swizzled
  const int tid = threadIdx.x;
  const int w = tid >> 6, lane = tid & 63;
  const int q = lane & 31, hi = lane >> 5;
  const int bh = blockIdx.y;
  const int b = bh >> 5, h = bh & 31;
  const int kvh = h >> 2;                        // GQA: H/KV = 4
  const int bxr = gridDim.x - 1 - blockIdx.x;    // longest blocks first
  const int q0 = bxr * 256;
  const int qw = q0 + w * 32;
  const int ntiles = 4 * bxr + 4;
  const int qg = qw + q;

  const u16* Qb = Qr + ((size_t)bh * Ssz + qw + q) * Dsz + hi * 8;
  bf16x8 qf[8];
#pragma unroll
  for (int ds = 0; ds < 8; ++ds)
    qf[ds] = __builtin_bit_cast(bf16x8, *(const u16x8*)(Qb + ds * 16));

  f32x16 oacc[4];
#pragma unroll
  for (int dt = 0; dt < 4; ++dt)
#pragma unroll
    for (int r = 0; r < 16; ++r) oacc[dt][r] = 0.f;
  float mr = -1e30f, lr = 0.f;

  const char* Kbase = (const char*)(Kr + (size_t)(b * KVsz + kvh) * Ssz * Dsz);
  const char* Vbase = (const char*)(Vt + (size_t)(b * KVsz + kvh) * Dsz * Ssz);

  auto STAGE = [&](int bu, int kt2) {
    const char* Kb = Kbase + (size_t)kt2 * (64 * 256);
    const char* Vb = Vbase + (size_t)kt2 * 128;   // 64 cols * 2B
#pragma unroll
    for (int j = 0; j < 2; ++j) {
      int flat = j * 512 + tid;
      int row = flat >> 4, colb = ((flat & 15) * 16) ^ ((row & 7) << 4);
      GLDS(Kb + (size_t)row * 256 + colb, (char*)&Kl[bu][0] + flat * 16);
    }
#pragma unroll
    for (int j = 0; j < 2; ++j) {
      int flat = j * 512 + tid;
      int row = flat >> 3, colb = ((flat & 7) * 16) ^ ((row & 7) << 4);
      GLDS(Vb + (size_t)row * (Ssz * 2) + colb, (char*)&Vl[bu][0] + flat * 16);
    }
  };

  int buf = 0;
  STAGE(0, 0);
  __syncthreads();

  for (int kt = 0; kt < ntiles; ++kt) {
    const int k0 = kt * 64;
    if (kt + 1 < ntiles) STAGE(buf ^ 1, kt + 1);   // prefetch overlaps compute

    if (k0 <= qw + 31) {                           // wave participates
      f32x16 pa0, pa1;
#pragma unroll
      for (int r = 0; r < 16; ++r) { pa0[r] = 0.f; pa1[r] = 0.f; }
      __builtin_amdgcn_s_setprio(1);
#pragma unroll
      for (int ds = 0; ds < 8; ++ds) {
        {
          const int row = q;
          const char* kp = (const char*)&Kl[buf][0] + row * 256 +
                           ((ds * 32 + hi * 16) ^ ((row & 7) << 4));
          bf16x8 kf = __builtin_bit_cast(bf16x8, *(const u16x8*)kp);
          pa0 = __builtin_amdgcn_mfma_f32_32x32x16_bf16(kf, qf[ds], pa0, 0, 0, 0);
        }
        {
          const int row = 32 + q;
          const char* kp = (const char*)&Kl[buf][0] + row * 256 +
                           ((ds * 32 + hi * 16) ^ ((row & 7) << 4));
          bf16x8 kf = __builtin_bit_cast(bf16x8, *(const u16x8*)kp);
          pa1 = __builtin_amdgcn_mfma_f32_32x32x16_bf16(kf, qf[ds], pa1, 0, 0, 0);
        }
      }
      __builtin_amdgcn_s_setprio(0);

      if (k0 + 63 > qw) {
#pragma unroll
        for (int reg = 0; reg < 16; ++reg) {
          const int kb = (reg & 3) + 8 * (reg >> 2) + 4 * hi;
          if (k0 + kb > qg)      pa0[reg] = -1e30f;
          if (k0 + 32 + kb > qg) pa1[reg] = -1e30f;
        }
      }
      float mx = -1e30f;
#pragma unroll
      for (int reg = 0; reg < 16; ++reg) mx = fmaxf(mx, fmaxf(pa0[reg], pa1[reg]));
      mx = fmaxf(mx, __shfl_xor(mx, 32, 64));
      const float mnew = fmaxf(mr, mx);
      const float corr = __expf(mr - mnew);
      float ps = 0.f;
#pragma unroll
      for (int reg = 0; reg < 16; ++reg) {
        pa0[reg] = __expf(pa0[reg] - mnew);
        pa1[reg] = __expf(pa1[reg] - mnew);
        ps += pa0[reg] + pa1[reg];
      }
      ps += __shfl_xor(ps, 32, 64);
      lr = lr * corr + ps;
      mr = mnew;
#pragma unroll
      for (int dt = 0; dt < 4; ++dt)
#pragma unroll
        for (int reg = 0; reg < 16; ++reg) oacc[dt][reg] *= corr;

      uint32_t W[2][4][2], X[2][4][2];
#pragma unroll
      for (int r2 = 0; r2 < 4; ++r2)
#pragma unroll
        for (int c = 0; c < 2; ++c) {
          W[0][r2][c] = packbf2(pa0[4 * r2 + 2 * c], pa0[4 * r2 + 2 * c + 1]);
          W[1][r2][c] = packbf2(pa1[4 * r2 + 2 * c], pa1[4 * r2 + 2 * c + 1]);
        }
#pragma unroll
      for (int T = 0; T < 2; ++T)
#pragma unroll
        for (int r2 = 0; r2 < 4; ++r2)
#pragma unroll
          for (int c = 0; c < 2; ++c)
            X[T][r2][c] = __shfl_xor(W[T][r2][c], 32, 64);

      __builtin_amdgcn_s_setprio(1);
#pragma unroll
      for (int ks = 0; ks < 4; ++ks) {
        const int T = ks >> 1, r2e = 2 * (ks & 1);
        u32x4 fw;
        fw[0] = hi ? X[T][r2e + 1][0] : W[T][r2e][0];
        fw[1] = hi ? X[T][r2e + 1][1] : W[T][r2e][1];
        fw[2] = hi ? W[T][r2e + 1][0] : X[T][r2e][0];
        fw[3] = hi ? W[T][r2e + 1][1] : X[T][r2e][1];
        bf16x8 pf = __builtin_bit_cast(bf16x8, fw);
#pragma unroll
        for (int dt = 0; dt < 4; ++dt) {
          const int row = dt * 32 + q;
          const char* vp = (const char*)&Vl[buf][0] + row * 128 +
                           ((ks * 32 + hi * 16) ^ ((row & 7) << 4));
          bf16x8 vf = __builtin_bit_cast(bf16x8, *(const u16x8*)vp);
          oacc[dt] = __builtin_amdgcn_mfma_f32_32x32x16_bf16(vf, pf, oacc[dt], 0, 0, 0);
        }
      }
      __builtin_amdgcn_s_setprio(0);
    }
    __syncthreads();                             // drains vmcnt: next buffer ready
    buf ^= 1;
  }

  const float inv = 1.f / lr;
  u16* Ob = AO + ((size_t)(b * Ssz) + qw + q) * HIDsz + h * Dsz + hi * 4;
#pragma unroll
  for (int dt = 0; dt < 4; ++dt)
#pragma unroll
    for (int r2 = 0; r2 < 4; ++r2) {
      u16x4 o4;
#pragma unroll
      for (int j = 0; j < 4; ++j) o4[j] = f2bf(oacc[dt][4 * r2 + j] * inv);
      *(u16x4*)(Ob + dt * 32 + r2 * 8) = o4;
    }
}

// ---------------- host ----------------
extern "C" void kernel_launch(void* const* d_in, const int* in_sizes, int n_in,
                              void* d_out, int out_size, void* d_ws, size_t ws_size,
                              hipStream_t stream) {
  (void)in_sizes; (void)n_in; (void)out_size;
  const float* hs   = (const float*)d_in[0];
  const int*   pos  = (const int*)d_in[1];
  const float* Wqkv = (const float*)d_in[2];
  const float* Wo   = (const float*)d_in[3];

  char* ws = (char*)d_ws;
  const size_t SZ_XBF = (size_t)4096 * 4096 * 2;   // also reused for AO
  const size_t SZ_WQ  = (size_t)6144 * 4096 * 2;
  const size_t SZ_WO  = (size_t)4096 * 4096 * 2;
  const size_t SZ_QKV = (size_t)4096 * 6144 * 2;
  const size_t SZ_QR  = (size_t)Bsz * Hsz * Ssz * Dsz * 2;
  const size_t SZ_KR  = (size_t)Bsz * KVsz * Ssz * Dsz * 2;
  const size_t SZ_VT  = SZ_KR;
  const size_t SZ_CS  = (size_t)Bsz * Ssz * 64 * 4;

  size_t off = 0;
  u16*   Xbf   = (u16*)(ws + off);  off += SZ_XBF;
  u16*   Wq_bf = (u16*)(ws + off);  off += SZ_WQ;
  u16*   Wo_bf = (u16*)(ws + off);  off += SZ_WO;
  u16*   qkv   = (u16*)(ws + off);  off += SZ_QKV;
  u16*   Qr    = (u16*)(ws + off);  off += SZ_QR;
  u16*   Kr    = (u16*)(ws + off);  off += SZ_KR;
  u16*   Vt    = (u16*)(ws + off);  off += SZ_VT;
  float* cosT  = (float*)(ws + off); off += SZ_CS;
  float* sinT  = (float*)(ws + off); off += SZ_CS;
  u16*   AO    = Xbf;                               // alias (Xbf dead after gemm1)
  if (ws_size < off) return;                        // fail loudly

  // 1. fp32 -> bf16 conversions
  k_cvt_bf16<<<(Bsz * Ssz * HIDsz) / 1024, 256, 0, stream>>>(hs, Xbf, (Bsz * Ssz * HIDsz) / 4);
  k_cvt_bf16<<<(NQKV * HIDsz) / 1024, 256, 0, stream>>>(Wqkv, Wq_bf, (NQKV * HIDsz) / 4);
  k_cvt_bf16<<<(HIDsz * HIDsz) / 1024, 256, 0, stream>>>(Wo, Wo_bf, (HIDsz * HIDsz) / 4);

  // 2. QKV projection: [4096,4096] x [6144,4096]^T -> [4096,6144]
  k_gemm256<true><<<dim3((NQKV / 256) * ((Bsz * Ssz) / 256)), 512, 0, stream>>>(
      Xbf, Wq_bf, qkv, Bsz * Ssz, NQKV, HIDsz);

  // 3. RoPE tables + apply + V transpose
  k_cs<<<(Bsz * Ssz * 64) / 256, 256, 0, stream>>>(pos, cosT, sinT);
  k_rope<<<(Bsz * Ssz * (Hsz + KVsz) * 64) / 256, 256, 0, stream>>>(qkv, cosT, sinT, Qr, Kr);
  k_vtrans<<<dim3(64, Bsz * KVsz), 256, 0, stream>>>(qkv, Vt);

  // 4. causal GQA attention -> AO [B,S,H*D] bf16
  k_attn<<<dim3(Ssz / 256, Bsz * Hsz), 512, 0, stream>>>(Qr, Kr, Vt, AO);

  // 5. o_proj: [4096,4096] x [4096,4096]^T -> d_out fp32
  k_gemm256<false><<<dim3((HIDsz / 256) * ((Bsz * Ssz) / 256)), 512, 0, stream>>>(
      AO, Wo_bf, (float*)d_out, Bsz * Ssz, HIDsz, HIDsz);
}